// Round 1
// baseline (1383.129 us; speedup 1.0000x reference)
//
#include <hip/hip_runtime.h>
#include <hip/hip_bf16.h>

#define NNODES 100000
#define NEDGES 1600000
#define EPSBN 1e-5f

// ---------------- CSR build ----------------

__global__ __launch_bounds__(256) void k_count(const int* __restrict__ ei, int* __restrict__ degcnt) {
    int e = blockIdx.x * 256 + threadIdx.x;
    if (e < NEDGES) {
        int d = ei[NEDGES + e];  // dst row
        atomicAdd(&degcnt[d], 1);
    }
}

#define SCAN_BLK 256
#define SCAN_ELEMS 1024

__global__ __launch_bounds__(256) void k_scan1(const int* __restrict__ in, int* __restrict__ out,
                                               int* __restrict__ bsums, int n) {
    __shared__ int sdata[SCAN_BLK];
    int base = blockIdx.x * SCAN_ELEMS;
    int idx = base + threadIdx.x * 4;
    int v0 = (idx + 0 < n) ? in[idx + 0] : 0;
    int v1 = (idx + 1 < n) ? in[idx + 1] : 0;
    int v2 = (idx + 2 < n) ? in[idx + 2] : 0;
    int v3 = (idx + 3 < n) ? in[idx + 3] : 0;
    int tsum = v0 + v1 + v2 + v3;
    int val = tsum;
    sdata[threadIdx.x] = val;
    __syncthreads();
    for (int off = 1; off < SCAN_BLK; off <<= 1) {
        int add = (threadIdx.x >= off) ? sdata[threadIdx.x - off] : 0;
        __syncthreads();
        val += add;
        sdata[threadIdx.x] = val;
        __syncthreads();
    }
    int excl = val - tsum;
    if (threadIdx.x == SCAN_BLK - 1) bsums[blockIdx.x] = val;
    if (idx + 0 < n) out[idx + 0] = excl;
    if (idx + 1 < n) out[idx + 1] = excl + v0;
    if (idx + 2 < n) out[idx + 2] = excl + v0 + v1;
    if (idx + 3 < n) out[idx + 3] = excl + v0 + v1 + v2;
}

__global__ __launch_bounds__(256) void k_scan2(int* __restrict__ bsums, int nb) {
    __shared__ int sdata[256];
    int v = (threadIdx.x < nb) ? bsums[threadIdx.x] : 0;
    int val = v;
    sdata[threadIdx.x] = val;
    __syncthreads();
    for (int off = 1; off < 256; off <<= 1) {
        int add = (threadIdx.x >= off) ? sdata[threadIdx.x - off] : 0;
        __syncthreads();
        val += add;
        sdata[threadIdx.x] = val;
        __syncthreads();
    }
    if (threadIdx.x < nb) bsums[threadIdx.x] = val - v;
}

__global__ __launch_bounds__(256) void k_scan3(int* __restrict__ out, const int* __restrict__ bsums, int n) {
    int idx = blockIdx.x * 256 + threadIdx.x;
    if (idx < n) out[idx] += bsums[idx / SCAN_ELEMS];
    if (idx == 0) out[n] = NEDGES;
}

__global__ __launch_bounds__(256) void k_dinv_cursor(const int* __restrict__ degcnt,
                                                     const int* __restrict__ rowptr,
                                                     float* __restrict__ dinv, int* __restrict__ cursor) {
    int i = blockIdx.x * 256 + threadIdx.x;
    if (i < NNODES) {
        dinv[i] = rsqrtf((float)(degcnt[i] + 1));  // deg includes self-loop, >= 1
        cursor[i] = rowptr[i];
    }
}

__global__ __launch_bounds__(256) void k_fill(const int* __restrict__ ei, int* __restrict__ cursor,
                                              int* __restrict__ colsrc) {
    int e = blockIdx.x * 256 + threadIdx.x;
    if (e < NEDGES) {
        int s = ei[e];
        int d = ei[NEDGES + e];
        int p = atomicAdd(&cursor[d], 1);
        colsrc[p] = s;
    }
}

// ---------------- GEMM: B[r][c] = dinv[r] * sum_k X[r][k]*W[k][c] ----------------

template <int COUT>
__global__ __launch_bounds__(256) void k_gemm_dinv(const float* __restrict__ X, const float* __restrict__ W,
                                                   const float* __restrict__ dinv, float* __restrict__ Bout,
                                                   int n) {
    constexpr int ROWS = 16;
    constexpr int NG = 256 / COUT;   // row-groups per block
    constexpr int RPT = ROWS / NG;   // rows per thread
    __shared__ float Ws[128 * COUT];
    __shared__ float Xs[ROWS * 128];
    const int tid = threadIdx.x;
    const int r0 = blockIdx.x * ROWS;
    for (int i = tid; i < 128 * COUT; i += 256) Ws[i] = W[i];
    for (int i = tid; i < ROWS * 128; i += 256) {
        int r = r0 + (i >> 7);
        Xs[i] = (r < n) ? X[(size_t)r * 128 + (i & 127)] : 0.f;
    }
    __syncthreads();
    const int col = tid % COUT;
    const int grp = tid / COUT;
    float acc[RPT];
#pragma unroll
    for (int i = 0; i < RPT; ++i) acc[i] = 0.f;
    for (int k = 0; k < 128; k += 4) {
        float w0 = Ws[(k + 0) * COUT + col];
        float w1 = Ws[(k + 1) * COUT + col];
        float w2 = Ws[(k + 2) * COUT + col];
        float w3 = Ws[(k + 3) * COUT + col];
#pragma unroll
        for (int i = 0; i < RPT; ++i) {
            int row = grp * RPT + i;
            const float4 xv = *(const float4*)&Xs[row * 128 + k];
            acc[i] += xv.x * w0 + xv.y * w1 + xv.z * w2 + xv.w * w3;
        }
    }
#pragma unroll
    for (int i = 0; i < RPT; ++i) {
        int r = r0 + grp * RPT + i;
        if (r < n) Bout[(size_t)r * COUT + col] = dinv[r] * acc[i];
    }
}

// ---------------- Aggregation: one wave per node ----------------
// Out[d][c] = dinv[d]*(B[d][c] + sum_{s in edges(d)} B[s][c]) + bias[c]
// (B already carries dinv[s] from the GEMM epilogue)

__global__ __launch_bounds__(256) void k_agg128(const float* __restrict__ Bm, const float* __restrict__ dinv,
                                                const int* __restrict__ rowptr, const int* __restrict__ colsrc,
                                                const float* __restrict__ bias, float* __restrict__ Out) {
    int node = blockIdx.x * 4 + (threadIdx.x >> 6);
    if (node >= NNODES) return;
    int lane = threadIdx.x & 63;
    const float2* B2 = (const float2*)Bm;
    float2 acc;
    // self loop term
    acc = B2[(size_t)node * 64 + lane];
    int beg = rowptr[node], end = rowptr[node + 1];
    for (int e = beg; e < end; ++e) {
        int s = colsrc[e];
        float2 v = B2[(size_t)s * 64 + lane];
        acc.x += v.x;
        acc.y += v.y;
    }
    float dv = dinv[node];
    float2 b = ((const float2*)bias)[lane];
    float2 o;
    o.x = dv * acc.x + b.x;
    o.y = dv * acc.y + b.y;
    ((float2*)Out)[(size_t)node * 64 + lane] = o;
}

__global__ __launch_bounds__(256) void k_agg64(const float* __restrict__ Bm, const float* __restrict__ dinv,
                                               const int* __restrict__ rowptr, const int* __restrict__ colsrc,
                                               const float* __restrict__ bias, float* __restrict__ Out) {
    int node = blockIdx.x * 4 + (threadIdx.x >> 6);
    if (node >= NNODES) return;
    int lane = threadIdx.x & 63;
    float acc = Bm[(size_t)node * 64 + lane];  // self loop
    int beg = rowptr[node], end = rowptr[node + 1];
    for (int e = beg; e < end; ++e) {
        int s = colsrc[e];
        acc += Bm[(size_t)s * 64 + lane];
    }
    Out[(size_t)node * 64 + lane] = dinv[node] * acc + bias[lane];
}

// ---------------- BatchNorm + ReLU ----------------

__global__ __launch_bounds__(256) void k_bn_stats(const float* __restrict__ H, float* __restrict__ sums,
                                                  float* __restrict__ sumsq) {
    int c = threadIdx.x & 127;
    int half = threadIdx.x >> 7;
    float s = 0.f, ss = 0.f;
    for (int r = blockIdx.x * 2 + half; r < NNODES; r += gridDim.x * 2) {
        float v = H[(size_t)r * 128 + c];
        s += v;
        ss += v * v;
    }
    __shared__ float red[256];
    red[threadIdx.x] = s;
    __syncthreads();
    if (half == 0) atomicAdd(&sums[c], s + red[128 + c]);
    __syncthreads();
    red[threadIdx.x] = ss;
    __syncthreads();
    if (half == 0) atomicAdd(&sumsq[c], ss + red[128 + c]);
}

__global__ void k_bn_final(const float* __restrict__ sums, const float* __restrict__ sumsq,
                           const float* __restrict__ g, const float* __restrict__ be,
                           float* __restrict__ scale, float* __restrict__ shift) {
    int c = threadIdx.x;  // 128 threads
    float mean = sums[c] * (1.0f / NNODES);
    float var = sumsq[c] * (1.0f / NNODES) - mean * mean;
    float istd = rsqrtf(var + EPSBN);
    float sc = g[c] * istd;
    scale[c] = sc;
    shift[c] = be[c] - sc * mean;
}

__global__ __launch_bounds__(256) void k_bn_apply(const float* __restrict__ H, const float* __restrict__ scale,
                                                  const float* __restrict__ shift, float* __restrict__ Out) {
    size_t i = (size_t)blockIdx.x * 256 + threadIdx.x;  // over N*128/4 float4s
    float4 v = ((const float4*)H)[i];
    int c = ((int)i & 31) * 4;
    v.x = fmaxf(v.x * scale[c + 0] + shift[c + 0], 0.f);
    v.y = fmaxf(v.y * scale[c + 1] + shift[c + 1], 0.f);
    v.z = fmaxf(v.z * scale[c + 2] + shift[c + 2], 0.f);
    v.w = fmaxf(v.w * scale[c + 3] + shift[c + 3], 0.f);
    ((float4*)Out)[i] = v;
}

// ---------------- launch ----------------

extern "C" void kernel_launch(void* const* d_in, const int* in_sizes, int n_in,
                              void* d_out, int out_size, void* d_ws, size_t ws_size,
                              hipStream_t stream) {
    const float* x   = (const float*)d_in[0];
    const float* W1  = (const float*)d_in[1];
    const float* b1  = (const float*)d_in[2];
    const float* g1  = (const float*)d_in[3];
    const float* be1 = (const float*)d_in[4];
    const float* W2  = (const float*)d_in[5];
    const float* b2  = (const float*)d_in[6];
    const float* g2  = (const float*)d_in[7];
    const float* be2 = (const float*)d_in[8];
    const float* W3  = (const float*)d_in[9];
    const float* b3  = (const float*)d_in[10];
    const int* ei    = (const int*)d_in[11];

    float* out_h = (float*)d_out;                        // [N,128] = h2 (post BN-ReLU layer 2)
    float* out_o = (float*)d_out + (size_t)NNODES * 128; // [N,64]  = conv3 output

    char* w = (char*)d_ws;
    float* A = (float*)w;      w += (size_t)NNODES * 128 * 4;
    float* Bm = (float*)w;     w += (size_t)NNODES * 128 * 4;
    float* dinv = (float*)w;   w += (size_t)NNODES * 4;
    int* degcnt = (int*)w;     w += (size_t)NNODES * 4;
    int* rowptr = (int*)w;     w += (size_t)(NNODES + 32) * 4;
    int* cursor = (int*)w;     w += (size_t)NNODES * 4;
    int* colsrc = (int*)w;     w += (size_t)NEDGES * 4;
    int* bsums = (int*)w;      w += 256 * 4;
    float* stats = (float*)w;  w += 768 * 4;
    float* sums1 = stats, *sumsq1 = stats + 128;
    float* sums2 = stats + 256, *sumsq2 = stats + 384;
    float* scale = stats + 512, *shift = stats + 640;

    const int EB = (NEDGES + 255) / 256;    // 6250
    const int NB = (NNODES + 255) / 256;    // 391
    const int SB = (NNODES + SCAN_ELEMS - 1) / SCAN_ELEMS;  // 98

    hipMemsetAsync(degcnt, 0, (size_t)NNODES * 4, stream);
    hipMemsetAsync(stats, 0, 512 * 4, stream);  // sums1,sumsq1,sums2,sumsq2

    // CSR build
    k_count<<<EB, 256, 0, stream>>>(ei, degcnt);
    k_scan1<<<SB, 256, 0, stream>>>(degcnt, rowptr, bsums, NNODES);
    k_scan2<<<1, 256, 0, stream>>>(bsums, SB);
    k_scan3<<<NB, 256, 0, stream>>>(rowptr, bsums, NNODES);
    k_dinv_cursor<<<NB, 256, 0, stream>>>(degcnt, rowptr, dinv, cursor);
    k_fill<<<EB, 256, 0, stream>>>(ei, cursor, colsrc);

    const int GB = NNODES / 16;    // 6250 gemm blocks
    const int AB = NNODES / 4;     // 25000 agg blocks (4 waves each)
    const int PB = (NNODES * 128 / 4) / 256;  // 12500 bn_apply blocks

    // Layer 1: x -> Bm -> A -> BN(A in place)
    k_gemm_dinv<128><<<GB, 256, 0, stream>>>(x, W1, dinv, Bm, NNODES);
    k_agg128<<<AB, 256, 0, stream>>>(Bm, dinv, rowptr, colsrc, b1, A);
    k_bn_stats<<<256, 256, 0, stream>>>(A, sums1, sumsq1);
    k_bn_final<<<1, 128, 0, stream>>>(sums1, sumsq1, g1, be1, scale, shift);
    k_bn_apply<<<PB, 256, 0, stream>>>(A, scale, shift, A);

    // Layer 2: A -> Bm -> A -> BN -> d_out (h2)
    k_gemm_dinv<128><<<GB, 256, 0, stream>>>(A, W2, dinv, Bm, NNODES);
    k_agg128<<<AB, 256, 0, stream>>>(Bm, dinv, rowptr, colsrc, b2, A);
    k_bn_stats<<<256, 256, 0, stream>>>(A, sums2, sumsq2);
    k_bn_final<<<1, 128, 0, stream>>>(sums2, sumsq2, g2, be2, scale, shift);
    k_bn_apply<<<PB, 256, 0, stream>>>(A, scale, shift, out_h);

    // Layer 3: h2 -> Bm(64) -> out
    k_gemm_dinv<64><<<GB, 256, 0, stream>>>(out_h, W3, dinv, Bm, NNODES);
    k_agg64<<<AB, 256, 0, stream>>>(Bm, dinv, rowptr, colsrc, b3, out_o);
}

// Round 2
// 942.843 us; speedup vs baseline: 1.4670x; 1.4670x over previous
//
#include <hip/hip_runtime.h>
#include <hip/hip_bf16.h>

#define NNODES 100000
#define NEDGES 1600000
#define EPSBN 1e-5f

typedef unsigned short u16;
typedef __bf16 bf16x8 __attribute__((ext_vector_type(8)));
typedef float floatx4 __attribute__((ext_vector_type(4)));

__device__ __forceinline__ u16 f2bf(float f) {
    unsigned int u = __float_as_uint(f);
    unsigned int r = (u + 0x7fffu + ((u >> 16) & 1u)) >> 16;
    return (u16)r;
}
__device__ __forceinline__ float bflo(unsigned int u) { return __uint_as_float(u << 16); }
__device__ __forceinline__ float bfhi(unsigned int u) { return __uint_as_float(u & 0xffff0000u); }

// ---------------- CSR build ----------------

__global__ __launch_bounds__(256) void k_count(const int* __restrict__ ei, int* __restrict__ degcnt) {
    int e = blockIdx.x * 256 + threadIdx.x;
    if (e < NEDGES) {
        int d = ei[NEDGES + e];
        atomicAdd(&degcnt[d], 1);
    }
}

#define SCAN_BLK 256
#define SCAN_ELEMS 1024

__global__ __launch_bounds__(256) void k_scan1(const int* __restrict__ in, int* __restrict__ out,
                                               int* __restrict__ bsums, int n) {
    __shared__ int sdata[SCAN_BLK];
    int base = blockIdx.x * SCAN_ELEMS;
    int idx = base + threadIdx.x * 4;
    int v0 = (idx + 0 < n) ? in[idx + 0] : 0;
    int v1 = (idx + 1 < n) ? in[idx + 1] : 0;
    int v2 = (idx + 2 < n) ? in[idx + 2] : 0;
    int v3 = (idx + 3 < n) ? in[idx + 3] : 0;
    int tsum = v0 + v1 + v2 + v3;
    int val = tsum;
    sdata[threadIdx.x] = val;
    __syncthreads();
    for (int off = 1; off < SCAN_BLK; off <<= 1) {
        int add = (threadIdx.x >= off) ? sdata[threadIdx.x - off] : 0;
        __syncthreads();
        val += add;
        sdata[threadIdx.x] = val;
        __syncthreads();
    }
    int excl = val - tsum;
    if (threadIdx.x == SCAN_BLK - 1) bsums[blockIdx.x] = val;
    if (idx + 0 < n) out[idx + 0] = excl;
    if (idx + 1 < n) out[idx + 1] = excl + v0;
    if (idx + 2 < n) out[idx + 2] = excl + v0 + v1;
    if (idx + 3 < n) out[idx + 3] = excl + v0 + v1 + v2;
}

__global__ __launch_bounds__(256) void k_scan2(int* __restrict__ bsums, int nb) {
    __shared__ int sdata[256];
    int v = (threadIdx.x < nb) ? bsums[threadIdx.x] : 0;
    int val = v;
    sdata[threadIdx.x] = val;
    __syncthreads();
    for (int off = 1; off < 256; off <<= 1) {
        int add = (threadIdx.x >= off) ? sdata[threadIdx.x - off] : 0;
        __syncthreads();
        val += add;
        sdata[threadIdx.x] = val;
        __syncthreads();
    }
    if (threadIdx.x < nb) bsums[threadIdx.x] = val - v;
}

__global__ __launch_bounds__(256) void k_scan3(int* __restrict__ out, const int* __restrict__ bsums, int n) {
    int idx = blockIdx.x * 256 + threadIdx.x;
    if (idx < n) out[idx] += bsums[idx / SCAN_ELEMS];
    if (idx == 0) out[n] = NEDGES;
}

__global__ __launch_bounds__(256) void k_dinv_cursor(const int* __restrict__ degcnt,
                                                     const int* __restrict__ rowptr,
                                                     float* __restrict__ dinv, int* __restrict__ cursor) {
    int i = blockIdx.x * 256 + threadIdx.x;
    if (i < NNODES) {
        dinv[i] = rsqrtf((float)(degcnt[i] + 1));
        cursor[i] = rowptr[i];
    }
}

__global__ __launch_bounds__(256) void k_fill(const int* __restrict__ ei, int* __restrict__ cursor,
                                              int* __restrict__ colsrc) {
    int e = blockIdx.x * 256 + threadIdx.x;
    if (e < NEDGES) {
        int s = ei[e];
        int d = ei[NEDGES + e];
        int p = atomicAdd(&cursor[d], 1);
        colsrc[p] = s;
    }
}

// ---------------- fp32 -> bf16 conversion ----------------

__global__ __launch_bounds__(256) void k_f2b(const float* __restrict__ in, u16* __restrict__ out, int n4) {
    int i = blockIdx.x * 256 + threadIdx.x;
    if (i >= n4) return;
    float4 v = ((const float4*)in)[i];
    ushort4 o;
    o.x = f2bf(v.x); o.y = f2bf(v.y); o.z = f2bf(v.z); o.w = f2bf(v.w);
    ((ushort4*)out)[i] = o;
}

// Pack W [128][COUT] fp32 into per-lane contiguous B-fragments:
// frag f = (ks*CT + ct)*64 + lane ; element j -> W[ks*32 + (lane>>4)*8 + j][ct*16 + (lane&15)]
template <int COUT>
__global__ void k_packW(const float* __restrict__ W, u16* __restrict__ Wp) {
    constexpr int CT = COUT / 16;
    int total = 4 * CT * 64;
    for (int f = threadIdx.x + blockIdx.x * blockDim.x; f < total; f += blockDim.x * gridDim.x) {
        int ks = f / (CT * 64);
        int ct = (f / 64) % CT;
        int lane = f % 64;
        int quad = lane >> 4, mm = lane & 15;
#pragma unroll
        for (int j = 0; j < 8; ++j) {
            float v = W[(size_t)(ks * 32 + quad * 8 + j) * COUT + ct * 16 + mm];
            Wp[(size_t)f * 8 + j] = f2bf(v);
        }
    }
}

// ---------------- MFMA GEMM: Bout[r][c] = bf16( dinv[r] * sum_k X[r][k]*W[k][c] ) ----------------

template <int COUT>
__global__ __launch_bounds__(256) void k_mfma_gemm(const u16* __restrict__ Xb, const u16* __restrict__ Wp,
                                                   const float* __restrict__ dinv, u16* __restrict__ Bout,
                                                   int n) {
    constexpr int CT = COUT / 16;
    const int wave = threadIdx.x >> 6;
    const int lane = threadIdx.x & 63;
    const int quad = lane >> 4;
    const int m = lane & 15;
    const int rowbase = blockIdx.x * 64 + wave * 16;
    floatx4 acc[CT];
#pragma unroll
    for (int ct = 0; ct < CT; ++ct) acc[ct] = floatx4{0.f, 0.f, 0.f, 0.f};
    const int arow = rowbase + m;
    const u16* aptr = Xb + (size_t)arow * 128 + quad * 8;
#pragma unroll
    for (int ks = 0; ks < 4; ++ks) {
        uint4 av = make_uint4(0u, 0u, 0u, 0u);
        if (arow < n) av = *(const uint4*)(aptr + ks * 32);
        bf16x8 a = *(const bf16x8*)&av;
#pragma unroll
        for (int ct = 0; ct < CT; ++ct) {
            uint4 bv = *(const uint4*)(Wp + ((size_t)(ks * CT + ct) * 64 + lane) * 8);
            bf16x8 b = *(const bf16x8*)&bv;
            acc[ct] = __builtin_amdgcn_mfma_f32_16x16x32_bf16(a, b, acc[ct], 0, 0, 0);
        }
    }
    float dv[4];
#pragma unroll
    for (int reg = 0; reg < 4; ++reg) {
        int r = rowbase + quad * 4 + reg;
        dv[reg] = (r < n) ? dinv[r] : 0.f;
    }
#pragma unroll
    for (int ct = 0; ct < CT; ++ct) {
#pragma unroll
        for (int reg = 0; reg < 4; ++reg) {
            int r = rowbase + quad * 4 + reg;
            if (r < n) Bout[(size_t)r * COUT + ct * 16 + m] = f2bf(dv[reg] * acc[ct][reg]);
        }
    }
}

// ---------------- Aggregation (bf16 messages, fp32 accumulate) ----------------
// Out[d][c] = dinv[d]*(B[d][c] + sum_{s in edges(d)} B[s][c]) + bias[c]

__global__ __launch_bounds__(256) void k_agg128b(const u16* __restrict__ Bm, const float* __restrict__ dinv,
                                                 const int* __restrict__ rowptr, const int* __restrict__ colsrc,
                                                 const float* __restrict__ bias, float* __restrict__ Out) {
    int node = blockIdx.x * 4 + (threadIdx.x >> 6);
    if (node >= NNODES) return;
    int lane = threadIdx.x & 63;
    const unsigned int* Bu = (const unsigned int*)Bm;  // 2 bf16 per uint
    unsigned int u = Bu[(size_t)node * 64 + lane];     // self loop
    float ax = bflo(u), ay = bfhi(u);
    int beg = rowptr[node], end = rowptr[node + 1];
    for (int e = beg; e < end; ++e) {
        int s = colsrc[e];
        unsigned int v = Bu[(size_t)s * 64 + lane];
        ax += bflo(v);
        ay += bfhi(v);
    }
    float dv = dinv[node];
    float2 b = ((const float2*)bias)[lane];
    float2 o;
    o.x = dv * ax + b.x;
    o.y = dv * ay + b.y;
    ((float2*)Out)[(size_t)node * 64 + lane] = o;
}

__global__ __launch_bounds__(256) void k_agg64b(const u16* __restrict__ Bm, const float* __restrict__ dinv,
                                                const int* __restrict__ rowptr, const int* __restrict__ colsrc,
                                                const float* __restrict__ bias, float* __restrict__ Out) {
    int node = blockIdx.x * 4 + (threadIdx.x >> 6);
    if (node >= NNODES) return;
    int lane = threadIdx.x & 63;
    float acc = __uint_as_float(((unsigned int)Bm[(size_t)node * 64 + lane]) << 16);  // self loop
    int beg = rowptr[node], end = rowptr[node + 1];
    for (int e = beg; e < end; ++e) {
        int s = colsrc[e];
        acc += __uint_as_float(((unsigned int)Bm[(size_t)s * 64 + lane]) << 16);
    }
    Out[(size_t)node * 64 + lane] = dinv[node] * acc + bias[lane];
}

// ---------------- BatchNorm + ReLU ----------------

__global__ __launch_bounds__(256) void k_bn_stats(const float* __restrict__ H, float* __restrict__ sums,
                                                  float* __restrict__ sumsq) {
    int c = threadIdx.x & 127;
    int half = threadIdx.x >> 7;
    float s = 0.f, ss = 0.f;
    for (int r = blockIdx.x * 2 + half; r < NNODES; r += gridDim.x * 2) {
        float v = H[(size_t)r * 128 + c];
        s += v;
        ss += v * v;
    }
    __shared__ float red[256];
    red[threadIdx.x] = s;
    __syncthreads();
    if (half == 0) atomicAdd(&sums[c], s + red[128 + c]);
    __syncthreads();
    red[threadIdx.x] = ss;
    __syncthreads();
    if (half == 0) atomicAdd(&sumsq[c], ss + red[128 + c]);
}

__global__ void k_bn_final(const float* __restrict__ sums, const float* __restrict__ sumsq,
                           const float* __restrict__ g, const float* __restrict__ be,
                           float* __restrict__ scale, float* __restrict__ shift) {
    int c = threadIdx.x;  // 128 threads
    float mean = sums[c] * (1.0f / NNODES);
    float var = sumsq[c] * (1.0f / NNODES) - mean * mean;
    float istd = rsqrtf(var + EPSBN);
    float sc = g[c] * istd;
    scale[c] = sc;
    shift[c] = be[c] - sc * mean;
}

// BN apply -> bf16 only (intermediate layer input to next GEMM)
__global__ __launch_bounds__(256) void k_bn_apply_b(const float* __restrict__ H, const float* __restrict__ scale,
                                                    const float* __restrict__ shift, u16* __restrict__ Ob) {
    size_t i = (size_t)blockIdx.x * 256 + threadIdx.x;
    float4 v = ((const float4*)H)[i];
    int c = ((int)i & 31) * 4;
    v.x = fmaxf(v.x * scale[c + 0] + shift[c + 0], 0.f);
    v.y = fmaxf(v.y * scale[c + 1] + shift[c + 1], 0.f);
    v.z = fmaxf(v.z * scale[c + 2] + shift[c + 2], 0.f);
    v.w = fmaxf(v.w * scale[c + 3] + shift[c + 3], 0.f);
    ushort4 o;
    o.x = f2bf(v.x); o.y = f2bf(v.y); o.z = f2bf(v.z); o.w = f2bf(v.w);
    ((ushort4*)Ob)[i] = o;
}

// BN apply -> fp32 output AND bf16 copy (layer 2: h2 is a required output + GEMM3 input)
__global__ __launch_bounds__(256) void k_bn_apply_fb(const float* __restrict__ H, const float* __restrict__ scale,
                                                     const float* __restrict__ shift, float* __restrict__ Of,
                                                     u16* __restrict__ Ob) {
    size_t i = (size_t)blockIdx.x * 256 + threadIdx.x;
    float4 v = ((const float4*)H)[i];
    int c = ((int)i & 31) * 4;
    v.x = fmaxf(v.x * scale[c + 0] + shift[c + 0], 0.f);
    v.y = fmaxf(v.y * scale[c + 1] + shift[c + 1], 0.f);
    v.z = fmaxf(v.z * scale[c + 2] + shift[c + 2], 0.f);
    v.w = fmaxf(v.w * scale[c + 3] + shift[c + 3], 0.f);
    ((float4*)Of)[i] = v;
    ushort4 o;
    o.x = f2bf(v.x); o.y = f2bf(v.y); o.z = f2bf(v.z); o.w = f2bf(v.w);
    ((ushort4*)Ob)[i] = o;
}

// ---------------- launch ----------------

extern "C" void kernel_launch(void* const* d_in, const int* in_sizes, int n_in,
                              void* d_out, int out_size, void* d_ws, size_t ws_size,
                              hipStream_t stream) {
    const float* x   = (const float*)d_in[0];
    const float* W1  = (const float*)d_in[1];
    const float* b1  = (const float*)d_in[2];
    const float* g1  = (const float*)d_in[3];
    const float* be1 = (const float*)d_in[4];
    const float* W2  = (const float*)d_in[5];
    const float* b2  = (const float*)d_in[6];
    const float* g2  = (const float*)d_in[7];
    const float* be2 = (const float*)d_in[8];
    const float* W3  = (const float*)d_in[9];
    const float* b3  = (const float*)d_in[10];
    const int* ei    = (const int*)d_in[11];

    float* out_h = (float*)d_out;                        // [N,128] h2
    float* out_o = (float*)d_out + (size_t)NNODES * 128; // [N,64]  conv3 out

    char* w = (char*)d_ws;
    float* A = (float*)w;      w += (size_t)NNODES * 128 * 4;   // fp32 post-agg
    u16* Bm = (u16*)w;         w += (size_t)NNODES * 128 * 2;   // bf16 messages
    u16* Hb = (u16*)w;         w += (size_t)NNODES * 128 * 2;   // bf16 GEMM input (Xb/Hb1/Hb2)
    float* dinv = (float*)w;   w += (size_t)NNODES * 4;
    int* degcnt = (int*)w;     w += (size_t)NNODES * 4;
    int* rowptr = (int*)w;     w += (size_t)(NNODES + 32) * 4;
    int* cursor = (int*)w;     w += (size_t)NNODES * 4;
    int* colsrc = (int*)w;     w += (size_t)NEDGES * 4;
    int* bsums = (int*)w;      w += 256 * 4;
    float* stats = (float*)w;  w += 768 * 4;
    u16* Wp1 = (u16*)w;        w += 128 * 128 * 2;
    u16* Wp2 = (u16*)w;        w += 128 * 128 * 2;
    u16* Wp3 = (u16*)w;        w += 128 * 64 * 2;
    float* sums1 = stats, *sumsq1 = stats + 128;
    float* sums2 = stats + 256, *sumsq2 = stats + 384;
    float* scale = stats + 512, *shift = stats + 640;

    const int EB = (NEDGES + 255) / 256;
    const int NB = (NNODES + 255) / 256;
    const int SB = (NNODES + SCAN_ELEMS - 1) / SCAN_ELEMS;

    hipMemsetAsync(degcnt, 0, (size_t)NNODES * 4, stream);
    hipMemsetAsync(stats, 0, 512 * 4, stream);

    // Input conversions (independent of CSR build)
    k_f2b<<<(NNODES * 128 / 4 + 255) / 256, 256, 0, stream>>>(x, Hb, NNODES * 128 / 4);
    k_packW<128><<<8, 256, 0, stream>>>(W1, Wp1);
    k_packW<128><<<8, 256, 0, stream>>>(W2, Wp2);
    k_packW<64><<<4, 256, 0, stream>>>(W3, Wp3);

    // CSR build
    k_count<<<EB, 256, 0, stream>>>(ei, degcnt);
    k_scan1<<<SB, 256, 0, stream>>>(degcnt, rowptr, bsums, NNODES);
    k_scan2<<<1, 256, 0, stream>>>(bsums, SB);
    k_scan3<<<NB, 256, 0, stream>>>(rowptr, bsums, NNODES);
    k_dinv_cursor<<<NB, 256, 0, stream>>>(degcnt, rowptr, dinv, cursor);
    k_fill<<<EB, 256, 0, stream>>>(ei, cursor, colsrc);

    const int GB = (NNODES + 63) / 64;       // 1563 mfma-gemm blocks (64 rows each)
    const int AB = (NNODES + 3) / 4;         // 25000 agg blocks (4 waves each)
    const int PB = (NNODES * 128 / 4) / 256; // 12500 bn_apply blocks

    // Layer 1: Hb(x bf16) -> Bm -> A -> BN -> Hb (bf16)
    k_mfma_gemm<128><<<GB, 256, 0, stream>>>(Hb, Wp1, dinv, Bm, NNODES);
    k_agg128b<<<AB, 256, 0, stream>>>(Bm, dinv, rowptr, colsrc, b1, A);
    k_bn_stats<<<1024, 256, 0, stream>>>(A, sums1, sumsq1);
    k_bn_final<<<1, 128, 0, stream>>>(sums1, sumsq1, g1, be1, scale, shift);
    k_bn_apply_b<<<PB, 256, 0, stream>>>(A, scale, shift, Hb);

    // Layer 2: Hb -> Bm -> A -> BN -> out_h (fp32) + Hb (bf16)
    k_mfma_gemm<128><<<GB, 256, 0, stream>>>(Hb, Wp2, dinv, Bm, NNODES);
    k_agg128b<<<AB, 256, 0, stream>>>(Bm, dinv, rowptr, colsrc, b2, A);
    k_bn_stats<<<1024, 256, 0, stream>>>(A, sums2, sumsq2);
    k_bn_final<<<1, 128, 0, stream>>>(sums2, sumsq2, g2, be2, scale, shift);
    k_bn_apply_fb<<<PB, 256, 0, stream>>>(A, scale, shift, out_h, Hb);

    // Layer 3: Hb -> Bm(64ch bf16) -> out_o (fp32)
    k_mfma_gemm<64><<<GB, 256, 0, stream>>>(Hb, Wp3, dinv, Bm, NNODES);
    k_agg64b<<<AB, 256, 0, stream>>>(Bm, dinv, rowptr, colsrc, b3, out_o);
}

// Round 3
// 669.225 us; speedup vs baseline: 2.0668x; 1.4089x over previous
//
#include <hip/hip_runtime.h>
#include <hip/hip_bf16.h>

#define NNODES 100000
#define NEDGES 1600000
#define EPSBN 1e-5f

typedef unsigned short u16;
typedef __bf16 bf16x8 __attribute__((ext_vector_type(8)));
typedef float floatx4 __attribute__((ext_vector_type(4)));

__device__ __forceinline__ u16 f2bf(float f) {
    unsigned int u = __float_as_uint(f);
    unsigned int r = (u + 0x7fffu + ((u >> 16) & 1u)) >> 16;
    return (u16)r;
}
__device__ __forceinline__ float bflo(unsigned int u) { return __uint_as_float(u << 16); }
__device__ __forceinline__ float bfhi(unsigned int u) { return __uint_as_float(u & 0xffff0000u); }

// ---------------- CSR build ----------------

__global__ __launch_bounds__(256) void k_count(const int* __restrict__ ei, int* __restrict__ degcnt) {
    int e = blockIdx.x * 256 + threadIdx.x;
    if (e < NEDGES) {
        int d = ei[NEDGES + e];
        atomicAdd(&degcnt[d], 1);
    }
}

#define SCAN_BLK 256
#define SCAN_ELEMS 1024

__global__ __launch_bounds__(256) void k_scan1(const int* __restrict__ in, int* __restrict__ out,
                                               int* __restrict__ bsums, int n) {
    __shared__ int sdata[SCAN_BLK];
    int base = blockIdx.x * SCAN_ELEMS;
    int idx = base + threadIdx.x * 4;
    int v0 = (idx + 0 < n) ? in[idx + 0] : 0;
    int v1 = (idx + 1 < n) ? in[idx + 1] : 0;
    int v2 = (idx + 2 < n) ? in[idx + 2] : 0;
    int v3 = (idx + 3 < n) ? in[idx + 3] : 0;
    int tsum = v0 + v1 + v2 + v3;
    int val = tsum;
    sdata[threadIdx.x] = val;
    __syncthreads();
    for (int off = 1; off < SCAN_BLK; off <<= 1) {
        int add = (threadIdx.x >= off) ? sdata[threadIdx.x - off] : 0;
        __syncthreads();
        val += add;
        sdata[threadIdx.x] = val;
        __syncthreads();
    }
    int excl = val - tsum;
    if (threadIdx.x == SCAN_BLK - 1) bsums[blockIdx.x] = val;
    if (idx + 0 < n) out[idx + 0] = excl;
    if (idx + 1 < n) out[idx + 1] = excl + v0;
    if (idx + 2 < n) out[idx + 2] = excl + v0 + v1;
    if (idx + 3 < n) out[idx + 3] = excl + v0 + v1 + v2;
}

__global__ __launch_bounds__(256) void k_scan2(int* __restrict__ bsums, int nb) {
    __shared__ int sdata[256];
    int v = (threadIdx.x < nb) ? bsums[threadIdx.x] : 0;
    int val = v;
    sdata[threadIdx.x] = val;
    __syncthreads();
    for (int off = 1; off < 256; off <<= 1) {
        int add = (threadIdx.x >= off) ? sdata[threadIdx.x - off] : 0;
        __syncthreads();
        val += add;
        sdata[threadIdx.x] = val;
        __syncthreads();
    }
    if (threadIdx.x < nb) bsums[threadIdx.x] = val - v;
}

__global__ __launch_bounds__(256) void k_scan3(int* __restrict__ out, const int* __restrict__ bsums, int n) {
    int idx = blockIdx.x * 256 + threadIdx.x;
    if (idx < n) out[idx] += bsums[idx / SCAN_ELEMS];
    if (idx == 0) out[n] = NEDGES;
}

__global__ __launch_bounds__(256) void k_dinv_cursor(const int* __restrict__ degcnt,
                                                     const int* __restrict__ rowptr,
                                                     float* __restrict__ dinv, int* __restrict__ cursor) {
    int i = blockIdx.x * 256 + threadIdx.x;
    if (i < NNODES) {
        dinv[i] = rsqrtf((float)(degcnt[i] + 1));
        cursor[i] = rowptr[i];
    }
}

__global__ __launch_bounds__(256) void k_fill(const int* __restrict__ ei, int* __restrict__ cursor,
                                              int* __restrict__ colsrc) {
    int e = blockIdx.x * 256 + threadIdx.x;
    if (e < NEDGES) {
        int s = ei[e];
        int d = ei[NEDGES + e];
        int p = atomicAdd(&cursor[d], 1);
        colsrc[p] = s;
    }
}

// ---------------- fp32 -> bf16 conversion ----------------

__global__ __launch_bounds__(256) void k_f2b(const float* __restrict__ in, u16* __restrict__ out, int n4) {
    int i = blockIdx.x * 256 + threadIdx.x;
    if (i >= n4) return;
    float4 v = ((const float4*)in)[i];
    ushort4 o;
    o.x = f2bf(v.x); o.y = f2bf(v.y); o.z = f2bf(v.z); o.w = f2bf(v.w);
    ((ushort4*)out)[i] = o;
}

// Pack W [128][COUT] fp32 into per-lane contiguous B-fragments
template <int COUT>
__global__ void k_packW(const float* __restrict__ W, u16* __restrict__ Wp) {
    constexpr int CT = COUT / 16;
    int total = 4 * CT * 64;
    for (int f = threadIdx.x + blockIdx.x * blockDim.x; f < total; f += blockDim.x * gridDim.x) {
        int ks = f / (CT * 64);
        int ct = (f / 64) % CT;
        int lane = f % 64;
        int quad = lane >> 4, mm = lane & 15;
#pragma unroll
        for (int j = 0; j < 8; ++j) {
            float v = W[(size_t)(ks * 32 + quad * 8 + j) * COUT + ct * 16 + mm];
            Wp[(size_t)f * 8 + j] = f2bf(v);
        }
    }
}

// ---------------- MFMA GEMM: Bout[r][c] = bf16( dinv[r] * sum_k X[r][k]*W[k][c] ) ----------------

template <int COUT>
__global__ __launch_bounds__(256) void k_mfma_gemm(const u16* __restrict__ Xb, const u16* __restrict__ Wp,
                                                   const float* __restrict__ dinv, u16* __restrict__ Bout,
                                                   int n) {
    constexpr int CT = COUT / 16;
    const int wave = threadIdx.x >> 6;
    const int lane = threadIdx.x & 63;
    const int quad = lane >> 4;
    const int m = lane & 15;
    const int rowbase = blockIdx.x * 64 + wave * 16;
    floatx4 acc[CT];
#pragma unroll
    for (int ct = 0; ct < CT; ++ct) acc[ct] = floatx4{0.f, 0.f, 0.f, 0.f};
    const int arow = rowbase + m;
    const u16* aptr = Xb + (size_t)arow * 128 + quad * 8;
#pragma unroll
    for (int ks = 0; ks < 4; ++ks) {
        uint4 av = make_uint4(0u, 0u, 0u, 0u);
        if (arow < n) av = *(const uint4*)(aptr + ks * 32);
        bf16x8 a = *(const bf16x8*)&av;
#pragma unroll
        for (int ct = 0; ct < CT; ++ct) {
            uint4 bv = *(const uint4*)(Wp + ((size_t)(ks * CT + ct) * 64 + lane) * 8);
            bf16x8 b = *(const bf16x8*)&bv;
            acc[ct] = __builtin_amdgcn_mfma_f32_16x16x32_bf16(a, b, acc[ct], 0, 0, 0);
        }
    }
    float dv[4];
#pragma unroll
    for (int reg = 0; reg < 4; ++reg) {
        int r = rowbase + quad * 4 + reg;
        dv[reg] = (r < n) ? dinv[r] : 0.f;
    }
#pragma unroll
    for (int ct = 0; ct < CT; ++ct) {
#pragma unroll
        for (int reg = 0; reg < 4; ++reg) {
            int r = rowbase + quad * 4 + reg;
            if (r < n) Bout[(size_t)r * COUT + ct * 16 + m] = f2bf(dv[reg] * acc[ct][reg]);
        }
    }
}

// ---------------- Aggregation (bf16 messages, fp32 accumulate, 8-wide MLP) ----------------
// Out[d][c] = dinv[d]*(B[d][c] + sum_{s in edges(d)} B[s][c]) + bias[c]

__global__ __launch_bounds__(256) void k_agg128b(const u16* __restrict__ Bm, const float* __restrict__ dinv,
                                                 const int* __restrict__ rowptr, const int* __restrict__ colsrc,
                                                 const float* __restrict__ bias, float* __restrict__ Out) {
    int node = blockIdx.x * 4 + (threadIdx.x >> 6);
    if (node >= NNODES) return;
    int lane = threadIdx.x & 63;
    const unsigned int* Bu = (const unsigned int*)Bm;  // 2 bf16 per uint
    unsigned int u = Bu[(size_t)node * 64 + lane];     // self loop
    float ax0 = bflo(u), ay0 = bfhi(u);
    float ax1 = 0.f, ay1 = 0.f, ax2 = 0.f, ay2 = 0.f, ax3 = 0.f, ay3 = 0.f;
    float ax4 = 0.f, ay4 = 0.f, ax5 = 0.f, ay5 = 0.f, ax6 = 0.f, ay6 = 0.f, ax7 = 0.f, ay7 = 0.f;
    int beg = rowptr[node], end = rowptr[node + 1];
    int e = beg;
    int full = beg + ((end - beg) & ~7);
    for (; e < full; e += 8) {
        int s0 = colsrc[e + 0], s1 = colsrc[e + 1], s2 = colsrc[e + 2], s3 = colsrc[e + 3];
        int s4 = colsrc[e + 4], s5 = colsrc[e + 5], s6 = colsrc[e + 6], s7 = colsrc[e + 7];
        unsigned int v0 = Bu[(size_t)s0 * 64 + lane];
        unsigned int v1 = Bu[(size_t)s1 * 64 + lane];
        unsigned int v2 = Bu[(size_t)s2 * 64 + lane];
        unsigned int v3 = Bu[(size_t)s3 * 64 + lane];
        unsigned int v4 = Bu[(size_t)s4 * 64 + lane];
        unsigned int v5 = Bu[(size_t)s5 * 64 + lane];
        unsigned int v6 = Bu[(size_t)s6 * 64 + lane];
        unsigned int v7 = Bu[(size_t)s7 * 64 + lane];
        ax0 += bflo(v0); ay0 += bfhi(v0);
        ax1 += bflo(v1); ay1 += bfhi(v1);
        ax2 += bflo(v2); ay2 += bfhi(v2);
        ax3 += bflo(v3); ay3 += bfhi(v3);
        ax4 += bflo(v4); ay4 += bfhi(v4);
        ax5 += bflo(v5); ay5 += bfhi(v5);
        ax6 += bflo(v6); ay6 += bfhi(v6);
        ax7 += bflo(v7); ay7 += bfhi(v7);
    }
    if (e < end) {
        // predicated tail batch: clamp index (extra gathers hit the same line in L1), weight invalid as 0
        int last = end - 1;
        int s0 = colsrc[min(e + 0, last)], s1 = colsrc[min(e + 1, last)];
        int s2 = colsrc[min(e + 2, last)], s3 = colsrc[min(e + 3, last)];
        int s4 = colsrc[min(e + 4, last)], s5 = colsrc[min(e + 5, last)];
        int s6 = colsrc[min(e + 6, last)], s7 = colsrc[min(e + 7, last)];
        unsigned int v0 = Bu[(size_t)s0 * 64 + lane];
        unsigned int v1 = Bu[(size_t)s1 * 64 + lane];
        unsigned int v2 = Bu[(size_t)s2 * 64 + lane];
        unsigned int v3 = Bu[(size_t)s3 * 64 + lane];
        unsigned int v4 = Bu[(size_t)s4 * 64 + lane];
        unsigned int v5 = Bu[(size_t)s5 * 64 + lane];
        unsigned int v6 = Bu[(size_t)s6 * 64 + lane];
        unsigned int v7 = Bu[(size_t)s7 * 64 + lane];
        float w1 = (e + 1 < end) ? 1.f : 0.f, w2 = (e + 2 < end) ? 1.f : 0.f;
        float w3 = (e + 3 < end) ? 1.f : 0.f, w4 = (e + 4 < end) ? 1.f : 0.f;
        float w5 = (e + 5 < end) ? 1.f : 0.f, w6 = (e + 6 < end) ? 1.f : 0.f;
        float w7 = (e + 7 < end) ? 1.f : 0.f;
        ax0 += bflo(v0); ay0 += bfhi(v0);
        ax1 += w1 * bflo(v1); ay1 += w1 * bfhi(v1);
        ax2 += w2 * bflo(v2); ay2 += w2 * bfhi(v2);
        ax3 += w3 * bflo(v3); ay3 += w3 * bfhi(v3);
        ax4 += w4 * bflo(v4); ay4 += w4 * bfhi(v4);
        ax5 += w5 * bflo(v5); ay5 += w5 * bfhi(v5);
        ax6 += w6 * bflo(v6); ay6 += w6 * bfhi(v6);
        ax7 += w7 * bflo(v7); ay7 += w7 * bfhi(v7);
    }
    float ax = ((ax0 + ax1) + (ax2 + ax3)) + ((ax4 + ax5) + (ax6 + ax7));
    float ay = ((ay0 + ay1) + (ay2 + ay3)) + ((ay4 + ay5) + (ay6 + ay7));
    float dv = dinv[node];
    float2 b = ((const float2*)bias)[lane];
    float2 o;
    o.x = dv * ax + b.x;
    o.y = dv * ay + b.y;
    ((float2*)Out)[(size_t)node * 64 + lane] = o;
}

__global__ __launch_bounds__(256) void k_agg64b(const u16* __restrict__ Bm, const float* __restrict__ dinv,
                                                const int* __restrict__ rowptr, const int* __restrict__ colsrc,
                                                const float* __restrict__ bias, float* __restrict__ Out) {
    int node = blockIdx.x * 4 + (threadIdx.x >> 6);
    if (node >= NNODES) return;
    int lane = threadIdx.x & 63;
    float a0 = __uint_as_float(((unsigned int)Bm[(size_t)node * 64 + lane]) << 16);  // self loop
    float a1 = 0.f, a2 = 0.f, a3 = 0.f, a4 = 0.f, a5 = 0.f, a6 = 0.f, a7 = 0.f;
    int beg = rowptr[node], end = rowptr[node + 1];
    int e = beg;
    int full = beg + ((end - beg) & ~7);
    for (; e < full; e += 8) {
        int s0 = colsrc[e + 0], s1 = colsrc[e + 1], s2 = colsrc[e + 2], s3 = colsrc[e + 3];
        int s4 = colsrc[e + 4], s5 = colsrc[e + 5], s6 = colsrc[e + 6], s7 = colsrc[e + 7];
        u16 v0 = Bm[(size_t)s0 * 64 + lane];
        u16 v1 = Bm[(size_t)s1 * 64 + lane];
        u16 v2 = Bm[(size_t)s2 * 64 + lane];
        u16 v3 = Bm[(size_t)s3 * 64 + lane];
        u16 v4 = Bm[(size_t)s4 * 64 + lane];
        u16 v5 = Bm[(size_t)s5 * 64 + lane];
        u16 v6 = Bm[(size_t)s6 * 64 + lane];
        u16 v7 = Bm[(size_t)s7 * 64 + lane];
        a0 += __uint_as_float(((unsigned int)v0) << 16);
        a1 += __uint_as_float(((unsigned int)v1) << 16);
        a2 += __uint_as_float(((unsigned int)v2) << 16);
        a3 += __uint_as_float(((unsigned int)v3) << 16);
        a4 += __uint_as_float(((unsigned int)v4) << 16);
        a5 += __uint_as_float(((unsigned int)v5) << 16);
        a6 += __uint_as_float(((unsigned int)v6) << 16);
        a7 += __uint_as_float(((unsigned int)v7) << 16);
    }
    if (e < end) {
        int last = end - 1;
        int s0 = colsrc[min(e + 0, last)], s1 = colsrc[min(e + 1, last)];
        int s2 = colsrc[min(e + 2, last)], s3 = colsrc[min(e + 3, last)];
        int s4 = colsrc[min(e + 4, last)], s5 = colsrc[min(e + 5, last)];
        int s6 = colsrc[min(e + 6, last)], s7 = colsrc[min(e + 7, last)];
        u16 v0 = Bm[(size_t)s0 * 64 + lane];
        u16 v1 = Bm[(size_t)s1 * 64 + lane];
        u16 v2 = Bm[(size_t)s2 * 64 + lane];
        u16 v3 = Bm[(size_t)s3 * 64 + lane];
        u16 v4 = Bm[(size_t)s4 * 64 + lane];
        u16 v5 = Bm[(size_t)s5 * 64 + lane];
        u16 v6 = Bm[(size_t)s6 * 64 + lane];
        u16 v7 = Bm[(size_t)s7 * 64 + lane];
        float w1 = (e + 1 < end) ? 1.f : 0.f, w2 = (e + 2 < end) ? 1.f : 0.f;
        float w3 = (e + 3 < end) ? 1.f : 0.f, w4 = (e + 4 < end) ? 1.f : 0.f;
        float w5 = (e + 5 < end) ? 1.f : 0.f, w6 = (e + 6 < end) ? 1.f : 0.f;
        float w7 = (e + 7 < end) ? 1.f : 0.f;
        a0 += __uint_as_float(((unsigned int)v0) << 16);
        a1 += w1 * __uint_as_float(((unsigned int)v1) << 16);
        a2 += w2 * __uint_as_float(((unsigned int)v2) << 16);
        a3 += w3 * __uint_as_float(((unsigned int)v3) << 16);
        a4 += w4 * __uint_as_float(((unsigned int)v4) << 16);
        a5 += w5 * __uint_as_float(((unsigned int)v5) << 16);
        a6 += w6 * __uint_as_float(((unsigned int)v6) << 16);
        a7 += w7 * __uint_as_float(((unsigned int)v7) << 16);
    }
    float acc = ((a0 + a1) + (a2 + a3)) + ((a4 + a5) + (a6 + a7));
    Out[(size_t)node * 64 + lane] = dinv[node] * acc + bias[lane];
}

// ---------------- BatchNorm + ReLU ----------------

__global__ __launch_bounds__(256) void k_bn_stats(const float* __restrict__ H, float* __restrict__ sums,
                                                  float* __restrict__ sumsq) {
    int c = threadIdx.x & 127;
    int half = threadIdx.x >> 7;
    float s = 0.f, ss = 0.f;
    for (int r = blockIdx.x * 2 + half; r < NNODES; r += gridDim.x * 2) {
        float v = H[(size_t)r * 128 + c];
        s += v;
        ss += v * v;
    }
    __shared__ float red[256];
    red[threadIdx.x] = s;
    __syncthreads();
    if (half == 0) atomicAdd(&sums[c], s + red[128 + c]);
    __syncthreads();
    red[threadIdx.x] = ss;
    __syncthreads();
    if (half == 0) atomicAdd(&sumsq[c], ss + red[128 + c]);
}

__global__ void k_bn_final(const float* __restrict__ sums, const float* __restrict__ sumsq,
                           const float* __restrict__ g, const float* __restrict__ be,
                           float* __restrict__ scale, float* __restrict__ shift) {
    int c = threadIdx.x;  // 128 threads
    float mean = sums[c] * (1.0f / NNODES);
    float var = sumsq[c] * (1.0f / NNODES) - mean * mean;
    float istd = rsqrtf(var + EPSBN);
    float sc = g[c] * istd;
    scale[c] = sc;
    shift[c] = be[c] - sc * mean;
}

// BN apply -> bf16 only (intermediate layer input to next GEMM)
__global__ __launch_bounds__(256) void k_bn_apply_b(const float* __restrict__ H, const float* __restrict__ scale,
                                                    const float* __restrict__ shift, u16* __restrict__ Ob) {
    size_t i = (size_t)blockIdx.x * 256 + threadIdx.x;
    float4 v = ((const float4*)H)[i];
    int c = ((int)i & 31) * 4;
    v.x = fmaxf(v.x * scale[c + 0] + shift[c + 0], 0.f);
    v.y = fmaxf(v.y * scale[c + 1] + shift[c + 1], 0.f);
    v.z = fmaxf(v.z * scale[c + 2] + shift[c + 2], 0.f);
    v.w = fmaxf(v.w * scale[c + 3] + shift[c + 3], 0.f);
    ushort4 o;
    o.x = f2bf(v.x); o.y = f2bf(v.y); o.z = f2bf(v.z); o.w = f2bf(v.w);
    ((ushort4*)Ob)[i] = o;
}

// BN apply -> fp32 output AND bf16 copy (layer 2: h2 is a required output + GEMM3 input)
__global__ __launch_bounds__(256) void k_bn_apply_fb(const float* __restrict__ H, const float* __restrict__ scale,
                                                     const float* __restrict__ shift, float* __restrict__ Of,
                                                     u16* __restrict__ Ob) {
    size_t i = (size_t)blockIdx.x * 256 + threadIdx.x;
    float4 v = ((const float4*)H)[i];
    int c = ((int)i & 31) * 4;
    v.x = fmaxf(v.x * scale[c + 0] + shift[c + 0], 0.f);
    v.y = fmaxf(v.y * scale[c + 1] + shift[c + 1], 0.f);
    v.z = fmaxf(v.z * scale[c + 2] + shift[c + 2], 0.f);
    v.w = fmaxf(v.w * scale[c + 3] + shift[c + 3], 0.f);
    ((float4*)Of)[i] = v;
    ushort4 o;
    o.x = f2bf(v.x); o.y = f2bf(v.y); o.z = f2bf(v.z); o.w = f2bf(v.w);
    ((ushort4*)Ob)[i] = o;
}

// ---------------- launch ----------------

extern "C" void kernel_launch(void* const* d_in, const int* in_sizes, int n_in,
                              void* d_out, int out_size, void* d_ws, size_t ws_size,
                              hipStream_t stream) {
    const float* x   = (const float*)d_in[0];
    const float* W1  = (const float*)d_in[1];
    const float* b1  = (const float*)d_in[2];
    const float* g1  = (const float*)d_in[3];
    const float* be1 = (const float*)d_in[4];
    const float* W2  = (const float*)d_in[5];
    const float* b2  = (const float*)d_in[6];
    const float* g2  = (const float*)d_in[7];
    const float* be2 = (const float*)d_in[8];
    const float* W3  = (const float*)d_in[9];
    const float* b3  = (const float*)d_in[10];
    const int* ei    = (const int*)d_in[11];

    float* out_h = (float*)d_out;                        // [N,128] h2
    float* out_o = (float*)d_out + (size_t)NNODES * 128; // [N,64]  conv3 out

    char* w = (char*)d_ws;
    float* A = (float*)w;      w += (size_t)NNODES * 128 * 4;   // fp32 post-agg
    u16* Bm = (u16*)w;         w += (size_t)NNODES * 128 * 2;   // bf16 messages
    u16* Hb = (u16*)w;         w += (size_t)NNODES * 128 * 2;   // bf16 GEMM input
    float* dinv = (float*)w;   w += (size_t)NNODES * 4;
    int* degcnt = (int*)w;     w += (size_t)NNODES * 4;
    int* rowptr = (int*)w;     w += (size_t)(NNODES + 32) * 4;
    int* cursor = (int*)w;     w += (size_t)NNODES * 4;
    int* colsrc = (int*)w;     w += (size_t)NEDGES * 4;
    int* bsums = (int*)w;      w += 256 * 4;
    float* stats = (float*)w;  w += 768 * 4;
    u16* Wp1 = (u16*)w;        w += 128 * 128 * 2;
    u16* Wp2 = (u16*)w;        w += 128 * 128 * 2;
    u16* Wp3 = (u16*)w;        w += 128 * 64 * 2;
    float* sums1 = stats, *sumsq1 = stats + 128;
    float* sums2 = stats + 256, *sumsq2 = stats + 384;
    float* scale = stats + 512, *shift = stats + 640;

    const int EB = (NEDGES + 255) / 256;
    const int NB = (NNODES + 255) / 256;
    const int SB = (NNODES + SCAN_ELEMS - 1) / SCAN_ELEMS;

    hipMemsetAsync(degcnt, 0, (size_t)NNODES * 4, stream);
    hipMemsetAsync(stats, 0, 512 * 4, stream);

    // Input conversions (independent of CSR build)
    k_f2b<<<(NNODES * 128 / 4 + 255) / 256, 256, 0, stream>>>(x, Hb, NNODES * 128 / 4);
    k_packW<128><<<8, 256, 0, stream>>>(W1, Wp1);
    k_packW<128><<<8, 256, 0, stream>>>(W2, Wp2);
    k_packW<64><<<4, 256, 0, stream>>>(W3, Wp3);

    // CSR build
    k_count<<<EB, 256, 0, stream>>>(ei, degcnt);
    k_scan1<<<SB, 256, 0, stream>>>(degcnt, rowptr, bsums, NNODES);
    k_scan2<<<1, 256, 0, stream>>>(bsums, SB);
    k_scan3<<<NB, 256, 0, stream>>>(rowptr, bsums, NNODES);
    k_dinv_cursor<<<NB, 256, 0, stream>>>(degcnt, rowptr, dinv, cursor);
    k_fill<<<EB, 256, 0, stream>>>(ei, cursor, colsrc);

    const int GB = (NNODES + 63) / 64;
    const int AB = (NNODES + 3) / 4;
    const int PB = (NNODES * 128 / 4) / 256;

    // Layer 1
    k_mfma_gemm<128><<<GB, 256, 0, stream>>>(Hb, Wp1, dinv, Bm, NNODES);
    k_agg128b<<<AB, 256, 0, stream>>>(Bm, dinv, rowptr, colsrc, b1, A);
    k_bn_stats<<<1024, 256, 0, stream>>>(A, sums1, sumsq1);
    k_bn_final<<<1, 128, 0, stream>>>(sums1, sumsq1, g1, be1, scale, shift);
    k_bn_apply_b<<<PB, 256, 0, stream>>>(A, scale, shift, Hb);

    // Layer 2
    k_mfma_gemm<128><<<GB, 256, 0, stream>>>(Hb, Wp2, dinv, Bm, NNODES);
    k_agg128b<<<AB, 256, 0, stream>>>(Bm, dinv, rowptr, colsrc, b2, A);
    k_bn_stats<<<1024, 256, 0, stream>>>(A, sums2, sumsq2);
    k_bn_final<<<1, 128, 0, stream>>>(sums2, sumsq2, g2, be2, scale, shift);
    k_bn_apply_fb<<<PB, 256, 0, stream>>>(A, scale, shift, out_h, Hb);

    // Layer 3
    k_mfma_gemm<64><<<GB, 256, 0, stream>>>(Hb, Wp3, dinv, Bm, NNODES);
    k_agg64b<<<AB, 256, 0, stream>>>(Bm, dinv, rowptr, colsrc, b3, out_o);
}

// Round 4
// 576.123 us; speedup vs baseline: 2.4008x; 1.1616x over previous
//
#include <hip/hip_runtime.h>
#include <hip/hip_bf16.h>

#define NNODES 100000
#define NEDGES 1600000
#define EPSBN 1e-5f

// CSR build via bucketed counting sort
#define BKT_SHIFT 9
#define NODES_PER_BKT 512               // 1 << BKT_SHIFT
#define NBKT 196                        // ceil(100000/512)
#define NCHUNK 256                      // scatter/hist chunks
#define CHUNK 6250                      // NEDGES / NCHUNK (exact)
#define SRC_MASK 0x1FFFF                // 17 bits, NNODES < 131072

typedef unsigned short u16;
typedef unsigned int u32;
typedef __bf16 bf16x8 __attribute__((ext_vector_type(8)));
typedef float floatx4 __attribute__((ext_vector_type(4)));

__device__ __forceinline__ u16 f2bf(float f) {
    unsigned int u = __float_as_uint(f);
    unsigned int r = (u + 0x7fffu + ((u >> 16) & 1u)) >> 16;
    return (u16)r;
}
__device__ __forceinline__ float bflo(unsigned int u) { return __uint_as_float(u << 16); }
__device__ __forceinline__ float bfhi(unsigned int u) { return __uint_as_float(u & 0xffff0000u); }

// ---------------- CSR build: bucketed counting sort ----------------

// Pass 1: per-chunk histogram over dst buckets -> histT[bucket][chunk]
__global__ __launch_bounds__(256) void k_hist(const int* __restrict__ ei, int* __restrict__ histT) {
    __shared__ int h[NBKT];
    int tid = threadIdx.x;
    if (tid < NBKT) h[tid] = 0;
    __syncthreads();
    int base = blockIdx.x * CHUNK;
    for (int e = base + tid; e < base + CHUNK; e += 256) {
        int d = ei[NEDGES + e];
        atomicAdd(&h[d >> BKT_SHIFT], 1);
    }
    __syncthreads();
    if (tid < NBKT) histT[tid * NCHUNK + blockIdx.x] = h[tid];
}

// Pass 2: bucket totals -> exclusive bucket bases; also sentinel rowptr[N]
__global__ __launch_bounds__(256) void k_bbase(const int* __restrict__ histT, int* __restrict__ bbase,
                                               int* __restrict__ rowptr) {
    __shared__ int sdata[256];
    int tid = threadIdx.x;
    int s = 0;
    if (tid < NBKT) {
        for (int g = 0; g < NCHUNK; ++g) s += histT[tid * NCHUNK + g];
    }
    int val = s;
    sdata[tid] = val;
    __syncthreads();
    for (int off = 1; off < 256; off <<= 1) {
        int add = (tid >= off) ? sdata[tid - off] : 0;
        __syncthreads();
        val += add;
        sdata[tid] = val;
        __syncthreads();
    }
    if (tid < NBKT) bbase[tid] = val - s;
    if (tid == 0) { bbase[NBKT] = NEDGES; rowptr[NNODES] = NEDGES; }
}

// Pass 3: per-(bucket,chunk) offsets: offT[b][g] = bbase[b] + excl_scan_g(histT[b][g])
__global__ __launch_bounds__(256) void k_bscan(const int* __restrict__ histT, const int* __restrict__ bbase,
                                               int* __restrict__ offT) {
    __shared__ int sdata[256];
    int b = blockIdx.x;
    int g = threadIdx.x;
    int v = histT[b * NCHUNK + g];
    int val = v;
    sdata[g] = val;
    __syncthreads();
    for (int off = 1; off < 256; off <<= 1) {
        int add = (g >= off) ? sdata[g - off] : 0;
        __syncthreads();
        val += add;
        sdata[g] = val;
        __syncthreads();
    }
    offT[b * NCHUNK + g] = bbase[b] + (val - v);
}

// Pass 4: scatter packed records (dstlow<<17 | src) into bucket-partitioned streams
__global__ __launch_bounds__(256) void k_scatter(const int* __restrict__ ei, const int* __restrict__ offT,
                                                 u32* __restrict__ rec) {
    __shared__ int cur[NBKT];
    int tid = threadIdx.x;
    if (tid < NBKT) cur[tid] = offT[tid * NCHUNK + blockIdx.x];
    __syncthreads();
    int base = blockIdx.x * CHUNK;
    for (int e = base + tid; e < base + CHUNK; e += 256) {
        int s = ei[e];
        int d = ei[NEDGES + e];
        int b = d >> BKT_SHIFT;
        int p = atomicAdd(&cur[b], 1);
        rec[p] = ((u32)(d & (NODES_PER_BKT - 1)) << 17) | (u32)s;
    }
}

// Pass 5: per-bucket: per-node counts (LDS) -> rowptr + dinv + colsrc fill (LDS cursors)
__global__ __launch_bounds__(256) void k_bfill(const u32* __restrict__ rec, const int* __restrict__ bbase,
                                               int* __restrict__ rowptr, float* __restrict__ dinv,
                                               int* __restrict__ colsrc) {
    __shared__ int cnt[NODES_PER_BKT];
    __shared__ int sdata[256];
    int tid = threadIdx.x;
    int b = blockIdx.x;
    int n0 = b * NODES_PER_BKT;
    int r0 = bbase[b], r1 = bbase[b + 1];
    cnt[2 * tid] = 0;
    cnt[2 * tid + 1] = 0;
    __syncthreads();
    for (int r = r0 + tid; r < r1; r += 256) {
        atomicAdd(&cnt[rec[r] >> 17], 1);
    }
    __syncthreads();
    int c0 = cnt[2 * tid], c1 = cnt[2 * tid + 1];
    int ps = c0 + c1;
    int val = ps;
    sdata[tid] = val;
    __syncthreads();
    for (int off = 1; off < 256; off <<= 1) {
        int add = (tid >= off) ? sdata[tid - off] : 0;
        __syncthreads();
        val += add;
        sdata[tid] = val;
        __syncthreads();
    }
    int e0 = val - ps;       // exclusive at node 2t
    int e1 = e0 + c0;        // exclusive at node 2t+1
    int na = n0 + 2 * tid, nb2 = n0 + 2 * tid + 1;
    if (na < NNODES) {
        rowptr[na] = r0 + e0;
        dinv[na] = rsqrtf((float)(c0 + 1));
    }
    if (nb2 < NNODES) {
        rowptr[nb2] = r0 + e1;
        dinv[nb2] = rsqrtf((float)(c1 + 1));
    }
    cnt[2 * tid] = r0 + e0;      // repurpose as cursors
    cnt[2 * tid + 1] = r0 + e1;
    __syncthreads();
    for (int r = r0 + tid; r < r1; r += 256) {
        u32 u = rec[r];
        int p = atomicAdd(&cnt[u >> 17], 1);
        colsrc[p] = (int)(u & SRC_MASK);
    }
}

// ---------------- fp32 -> bf16 conversion ----------------

__global__ __launch_bounds__(256) void k_f2b(const float* __restrict__ in, u16* __restrict__ out, int n4) {
    int i = blockIdx.x * 256 + threadIdx.x;
    if (i >= n4) return;
    float4 v = ((const float4*)in)[i];
    ushort4 o;
    o.x = f2bf(v.x); o.y = f2bf(v.y); o.z = f2bf(v.z); o.w = f2bf(v.w);
    ((ushort4*)out)[i] = o;
}

// Pack W [128][COUT] fp32 into per-lane contiguous B-fragments
template <int COUT>
__global__ void k_packW(const float* __restrict__ W, u16* __restrict__ Wp) {
    constexpr int CT = COUT / 16;
    int total = 4 * CT * 64;
    for (int f = threadIdx.x + blockIdx.x * blockDim.x; f < total; f += blockDim.x * gridDim.x) {
        int ks = f / (CT * 64);
        int ct = (f / 64) % CT;
        int lane = f % 64;
        int quad = lane >> 4, mm = lane & 15;
#pragma unroll
        for (int j = 0; j < 8; ++j) {
            float v = W[(size_t)(ks * 32 + quad * 8 + j) * COUT + ct * 16 + mm];
            Wp[(size_t)f * 8 + j] = f2bf(v);
        }
    }
}

// ---------------- MFMA GEMM: Bout[r][c] = bf16( dinv[r] * sum_k X[r][k]*W[k][c] ) ----------------

template <int COUT>
__global__ __launch_bounds__(256) void k_mfma_gemm(const u16* __restrict__ Xb, const u16* __restrict__ Wp,
                                                   const float* __restrict__ dinv, u16* __restrict__ Bout,
                                                   int n) {
    constexpr int CT = COUT / 16;
    const int wave = threadIdx.x >> 6;
    const int lane = threadIdx.x & 63;
    const int quad = lane >> 4;
    const int m = lane & 15;
    const int rowbase = blockIdx.x * 64 + wave * 16;
    floatx4 acc[CT];
#pragma unroll
    for (int ct = 0; ct < CT; ++ct) acc[ct] = floatx4{0.f, 0.f, 0.f, 0.f};
    const int arow = rowbase + m;
    const u16* aptr = Xb + (size_t)arow * 128 + quad * 8;
#pragma unroll
    for (int ks = 0; ks < 4; ++ks) {
        uint4 av = make_uint4(0u, 0u, 0u, 0u);
        if (arow < n) av = *(const uint4*)(aptr + ks * 32);
        bf16x8 a = *(const bf16x8*)&av;
#pragma unroll
        for (int ct = 0; ct < CT; ++ct) {
            uint4 bv = *(const uint4*)(Wp + ((size_t)(ks * CT + ct) * 64 + lane) * 8);
            bf16x8 b = *(const bf16x8*)&bv;
            acc[ct] = __builtin_amdgcn_mfma_f32_16x16x32_bf16(a, b, acc[ct], 0, 0, 0);
        }
    }
    float dv[4];
#pragma unroll
    for (int reg = 0; reg < 4; ++reg) {
        int r = rowbase + quad * 4 + reg;
        dv[reg] = (r < n) ? dinv[r] : 0.f;
    }
#pragma unroll
    for (int ct = 0; ct < CT; ++ct) {
#pragma unroll
        for (int reg = 0; reg < 4; ++reg) {
            int r = rowbase + quad * 4 + reg;
            if (r < n) Bout[(size_t)r * COUT + ct * 16 + m] = f2bf(dv[reg] * acc[ct][reg]);
        }
    }
}

// ---------------- Aggregation (bf16 messages, fp32 accumulate, 8-wide MLP) ----------------

__global__ __launch_bounds__(256) void k_agg128b(const u16* __restrict__ Bm, const float* __restrict__ dinv,
                                                 const int* __restrict__ rowptr, const int* __restrict__ colsrc,
                                                 const float* __restrict__ bias, float* __restrict__ Out) {
    int node = blockIdx.x * 4 + (threadIdx.x >> 6);
    if (node >= NNODES) return;
    int lane = threadIdx.x & 63;
    const unsigned int* Bu = (const unsigned int*)Bm;  // 2 bf16 per uint
    unsigned int u = Bu[(size_t)node * 64 + lane];     // self loop
    float ax0 = bflo(u), ay0 = bfhi(u);
    float ax1 = 0.f, ay1 = 0.f, ax2 = 0.f, ay2 = 0.f, ax3 = 0.f, ay3 = 0.f;
    float ax4 = 0.f, ay4 = 0.f, ax5 = 0.f, ay5 = 0.f, ax6 = 0.f, ay6 = 0.f, ax7 = 0.f, ay7 = 0.f;
    int beg = rowptr[node], end = rowptr[node + 1];
    int e = beg;
    int full = beg + ((end - beg) & ~7);
    for (; e < full; e += 8) {
        int s0 = colsrc[e + 0], s1 = colsrc[e + 1], s2 = colsrc[e + 2], s3 = colsrc[e + 3];
        int s4 = colsrc[e + 4], s5 = colsrc[e + 5], s6 = colsrc[e + 6], s7 = colsrc[e + 7];
        unsigned int v0 = Bu[(size_t)s0 * 64 + lane];
        unsigned int v1 = Bu[(size_t)s1 * 64 + lane];
        unsigned int v2 = Bu[(size_t)s2 * 64 + lane];
        unsigned int v3 = Bu[(size_t)s3 * 64 + lane];
        unsigned int v4 = Bu[(size_t)s4 * 64 + lane];
        unsigned int v5 = Bu[(size_t)s5 * 64 + lane];
        unsigned int v6 = Bu[(size_t)s6 * 64 + lane];
        unsigned int v7 = Bu[(size_t)s7 * 64 + lane];
        ax0 += bflo(v0); ay0 += bfhi(v0);
        ax1 += bflo(v1); ay1 += bfhi(v1);
        ax2 += bflo(v2); ay2 += bfhi(v2);
        ax3 += bflo(v3); ay3 += bfhi(v3);
        ax4 += bflo(v4); ay4 += bfhi(v4);
        ax5 += bflo(v5); ay5 += bfhi(v5);
        ax6 += bflo(v6); ay6 += bfhi(v6);
        ax7 += bflo(v7); ay7 += bfhi(v7);
    }
    if (e < end) {
        int last = end - 1;
        int s0 = colsrc[min(e + 0, last)], s1 = colsrc[min(e + 1, last)];
        int s2 = colsrc[min(e + 2, last)], s3 = colsrc[min(e + 3, last)];
        int s4 = colsrc[min(e + 4, last)], s5 = colsrc[min(e + 5, last)];
        int s6 = colsrc[min(e + 6, last)], s7 = colsrc[min(e + 7, last)];
        unsigned int v0 = Bu[(size_t)s0 * 64 + lane];
        unsigned int v1 = Bu[(size_t)s1 * 64 + lane];
        unsigned int v2 = Bu[(size_t)s2 * 64 + lane];
        unsigned int v3 = Bu[(size_t)s3 * 64 + lane];
        unsigned int v4 = Bu[(size_t)s4 * 64 + lane];
        unsigned int v5 = Bu[(size_t)s5 * 64 + lane];
        unsigned int v6 = Bu[(size_t)s6 * 64 + lane];
        unsigned int v7 = Bu[(size_t)s7 * 64 + lane];
        float w1 = (e + 1 < end) ? 1.f : 0.f, w2 = (e + 2 < end) ? 1.f : 0.f;
        float w3 = (e + 3 < end) ? 1.f : 0.f, w4 = (e + 4 < end) ? 1.f : 0.f;
        float w5 = (e + 5 < end) ? 1.f : 0.f, w6 = (e + 6 < end) ? 1.f : 0.f;
        float w7 = (e + 7 < end) ? 1.f : 0.f;
        ax0 += bflo(v0); ay0 += bfhi(v0);
        ax1 += w1 * bflo(v1); ay1 += w1 * bfhi(v1);
        ax2 += w2 * bflo(v2); ay2 += w2 * bfhi(v2);
        ax3 += w3 * bflo(v3); ay3 += w3 * bfhi(v3);
        ax4 += w4 * bflo(v4); ay4 += w4 * bfhi(v4);
        ax5 += w5 * bflo(v5); ay5 += w5 * bfhi(v5);
        ax6 += w6 * bflo(v6); ay6 += w6 * bfhi(v6);
        ax7 += w7 * bflo(v7); ay7 += w7 * bfhi(v7);
    }
    float ax = ((ax0 + ax1) + (ax2 + ax3)) + ((ax4 + ax5) + (ax6 + ax7));
    float ay = ((ay0 + ay1) + (ay2 + ay3)) + ((ay4 + ay5) + (ay6 + ay7));
    float dv = dinv[node];
    float2 b = ((const float2*)bias)[lane];
    float2 o;
    o.x = dv * ax + b.x;
    o.y = dv * ay + b.y;
    ((float2*)Out)[(size_t)node * 64 + lane] = o;
}

__global__ __launch_bounds__(256) void k_agg64b(const u16* __restrict__ Bm, const float* __restrict__ dinv,
                                                const int* __restrict__ rowptr, const int* __restrict__ colsrc,
                                                const float* __restrict__ bias, float* __restrict__ Out) {
    int node = blockIdx.x * 4 + (threadIdx.x >> 6);
    if (node >= NNODES) return;
    int lane = threadIdx.x & 63;
    float a0 = __uint_as_float(((unsigned int)Bm[(size_t)node * 64 + lane]) << 16);  // self loop
    float a1 = 0.f, a2 = 0.f, a3 = 0.f, a4 = 0.f, a5 = 0.f, a6 = 0.f, a7 = 0.f;
    int beg = rowptr[node], end = rowptr[node + 1];
    int e = beg;
    int full = beg + ((end - beg) & ~7);
    for (; e < full; e += 8) {
        int s0 = colsrc[e + 0], s1 = colsrc[e + 1], s2 = colsrc[e + 2], s3 = colsrc[e + 3];
        int s4 = colsrc[e + 4], s5 = colsrc[e + 5], s6 = colsrc[e + 6], s7 = colsrc[e + 7];
        u16 v0 = Bm[(size_t)s0 * 64 + lane];
        u16 v1 = Bm[(size_t)s1 * 64 + lane];
        u16 v2 = Bm[(size_t)s2 * 64 + lane];
        u16 v3 = Bm[(size_t)s3 * 64 + lane];
        u16 v4 = Bm[(size_t)s4 * 64 + lane];
        u16 v5 = Bm[(size_t)s5 * 64 + lane];
        u16 v6 = Bm[(size_t)s6 * 64 + lane];
        u16 v7 = Bm[(size_t)s7 * 64 + lane];
        a0 += __uint_as_float(((unsigned int)v0) << 16);
        a1 += __uint_as_float(((unsigned int)v1) << 16);
        a2 += __uint_as_float(((unsigned int)v2) << 16);
        a3 += __uint_as_float(((unsigned int)v3) << 16);
        a4 += __uint_as_float(((unsigned int)v4) << 16);
        a5 += __uint_as_float(((unsigned int)v5) << 16);
        a6 += __uint_as_float(((unsigned int)v6) << 16);
        a7 += __uint_as_float(((unsigned int)v7) << 16);
    }
    if (e < end) {
        int last = end - 1;
        int s0 = colsrc[min(e + 0, last)], s1 = colsrc[min(e + 1, last)];
        int s2 = colsrc[min(e + 2, last)], s3 = colsrc[min(e + 3, last)];
        int s4 = colsrc[min(e + 4, last)], s5 = colsrc[min(e + 5, last)];
        int s6 = colsrc[min(e + 6, last)], s7 = colsrc[min(e + 7, last)];
        u16 v0 = Bm[(size_t)s0 * 64 + lane];
        u16 v1 = Bm[(size_t)s1 * 64 + lane];
        u16 v2 = Bm[(size_t)s2 * 64 + lane];
        u16 v3 = Bm[(size_t)s3 * 64 + lane];
        u16 v4 = Bm[(size_t)s4 * 64 + lane];
        u16 v5 = Bm[(size_t)s5 * 64 + lane];
        u16 v6 = Bm[(size_t)s6 * 64 + lane];
        u16 v7 = Bm[(size_t)s7 * 64 + lane];
        float w1 = (e + 1 < end) ? 1.f : 0.f, w2 = (e + 2 < end) ? 1.f : 0.f;
        float w3 = (e + 3 < end) ? 1.f : 0.f, w4 = (e + 4 < end) ? 1.f : 0.f;
        float w5 = (e + 5 < end) ? 1.f : 0.f, w6 = (e + 6 < end) ? 1.f : 0.f;
        float w7 = (e + 7 < end) ? 1.f : 0.f;
        a0 += __uint_as_float(((unsigned int)v0) << 16);
        a1 += w1 * __uint_as_float(((unsigned int)v1) << 16);
        a2 += w2 * __uint_as_float(((unsigned int)v2) << 16);
        a3 += w3 * __uint_as_float(((unsigned int)v3) << 16);
        a4 += w4 * __uint_as_float(((unsigned int)v4) << 16);
        a5 += w5 * __uint_as_float(((unsigned int)v5) << 16);
        a6 += w6 * __uint_as_float(((unsigned int)v6) << 16);
        a7 += w7 * __uint_as_float(((unsigned int)v7) << 16);
    }
    float acc = ((a0 + a1) + (a2 + a3)) + ((a4 + a5) + (a6 + a7));
    Out[(size_t)node * 64 + lane] = dinv[node] * acc + bias[lane];
}

// ---------------- BatchNorm + ReLU ----------------

__global__ __launch_bounds__(256) void k_bn_stats(const float* __restrict__ H, float* __restrict__ sums,
                                                  float* __restrict__ sumsq) {
    int c = threadIdx.x & 127;
    int half = threadIdx.x >> 7;
    float s = 0.f, ss = 0.f;
    for (int r = blockIdx.x * 2 + half; r < NNODES; r += gridDim.x * 2) {
        float v = H[(size_t)r * 128 + c];
        s += v;
        ss += v * v;
    }
    __shared__ float red[256];
    red[threadIdx.x] = s;
    __syncthreads();
    if (half == 0) atomicAdd(&sums[c], s + red[128 + c]);
    __syncthreads();
    red[threadIdx.x] = ss;
    __syncthreads();
    if (half == 0) atomicAdd(&sumsq[c], ss + red[128 + c]);
}

__global__ void k_bn_final(const float* __restrict__ sums, const float* __restrict__ sumsq,
                           const float* __restrict__ g, const float* __restrict__ be,
                           float* __restrict__ scale, float* __restrict__ shift) {
    int c = threadIdx.x;  // 128 threads
    float mean = sums[c] * (1.0f / NNODES);
    float var = sumsq[c] * (1.0f / NNODES) - mean * mean;
    float istd = rsqrtf(var + EPSBN);
    float sc = g[c] * istd;
    scale[c] = sc;
    shift[c] = be[c] - sc * mean;
}

__global__ __launch_bounds__(256) void k_bn_apply_b(const float* __restrict__ H, const float* __restrict__ scale,
                                                    const float* __restrict__ shift, u16* __restrict__ Ob) {
    size_t i = (size_t)blockIdx.x * 256 + threadIdx.x;
    float4 v = ((const float4*)H)[i];
    int c = ((int)i & 31) * 4;
    v.x = fmaxf(v.x * scale[c + 0] + shift[c + 0], 0.f);
    v.y = fmaxf(v.y * scale[c + 1] + shift[c + 1], 0.f);
    v.z = fmaxf(v.z * scale[c + 2] + shift[c + 2], 0.f);
    v.w = fmaxf(v.w * scale[c + 3] + shift[c + 3], 0.f);
    ushort4 o;
    o.x = f2bf(v.x); o.y = f2bf(v.y); o.z = f2bf(v.z); o.w = f2bf(v.w);
    ((ushort4*)Ob)[i] = o;
}

__global__ __launch_bounds__(256) void k_bn_apply_fb(const float* __restrict__ H, const float* __restrict__ scale,
                                                     const float* __restrict__ shift, float* __restrict__ Of,
                                                     u16* __restrict__ Ob) {
    size_t i = (size_t)blockIdx.x * 256 + threadIdx.x;
    float4 v = ((const float4*)H)[i];
    int c = ((int)i & 31) * 4;
    v.x = fmaxf(v.x * scale[c + 0] + shift[c + 0], 0.f);
    v.y = fmaxf(v.y * scale[c + 1] + shift[c + 1], 0.f);
    v.z = fmaxf(v.z * scale[c + 2] + shift[c + 2], 0.f);
    v.w = fmaxf(v.w * scale[c + 3] + shift[c + 3], 0.f);
    ((float4*)Of)[i] = v;
    ushort4 o;
    o.x = f2bf(v.x); o.y = f2bf(v.y); o.z = f2bf(v.z); o.w = f2bf(v.w);
    ((ushort4*)Ob)[i] = o;
}

// ---------------- launch ----------------

extern "C" void kernel_launch(void* const* d_in, const int* in_sizes, int n_in,
                              void* d_out, int out_size, void* d_ws, size_t ws_size,
                              hipStream_t stream) {
    const float* x   = (const float*)d_in[0];
    const float* W1  = (const float*)d_in[1];
    const float* b1  = (const float*)d_in[2];
    const float* g1  = (const float*)d_in[3];
    const float* be1 = (const float*)d_in[4];
    const float* W2  = (const float*)d_in[5];
    const float* b2  = (const float*)d_in[6];
    const float* g2  = (const float*)d_in[7];
    const float* be2 = (const float*)d_in[8];
    const float* W3  = (const float*)d_in[9];
    const float* b3  = (const float*)d_in[10];
    const int* ei    = (const int*)d_in[11];

    float* out_h = (float*)d_out;                        // [N,128] h2
    float* out_o = (float*)d_out + (size_t)NNODES * 128; // [N,64]  conv3 out

    char* w = (char*)d_ws;
    float* A = (float*)w;      w += (size_t)NNODES * 128 * 4;   // fp32 post-agg
    u16* Bm = (u16*)w;         w += (size_t)NNODES * 128 * 2;   // bf16 messages
    u16* Hb = (u16*)w;         w += (size_t)NNODES * 128 * 2;   // bf16 GEMM input
    float* dinv = (float*)w;   w += (size_t)NNODES * 4;
    int* rowptr = (int*)w;     w += (size_t)(NNODES + 32) * 4;
    int* colsrc = (int*)w;     w += (size_t)NEDGES * 4;
    int* bbase = (int*)w;      w += (NBKT + 4) * 4;
    float* stats = (float*)w;  w += 768 * 4;
    u16* Wp1 = (u16*)w;        w += 128 * 128 * 2;
    u16* Wp2 = (u16*)w;        w += 128 * 128 * 2;
    u16* Wp3 = (u16*)w;        w += 128 * 64 * 2;
    float* sums1 = stats, *sumsq1 = stats + 128;
    float* sums2 = stats + 256, *sumsq2 = stats + 384;
    float* scale = stats + 512, *shift = stats + 640;

    // Build-phase scratch aliased onto buffers that are dead until layer 1:
    u32* rec  = (u32*)A;                        // [NEDGES] packed records (A written first by agg1)
    int* histT = (int*)Bm;                      // [NBKT*NCHUNK] (Bm written first by gemm1)
    int* offT  = (int*)Bm + NBKT * NCHUNK;      // [NBKT*NCHUNK]

    hipMemsetAsync(stats, 0, 512 * 4, stream);

    // Input conversions (independent of CSR build)
    k_f2b<<<(NNODES * 128 / 4 + 255) / 256, 256, 0, stream>>>(x, Hb, NNODES * 128 / 4);
    k_packW<128><<<8, 256, 0, stream>>>(W1, Wp1);
    k_packW<128><<<8, 256, 0, stream>>>(W2, Wp2);
    k_packW<64><<<4, 256, 0, stream>>>(W3, Wp3);

    // CSR build: bucketed counting sort (no global atomics, cache-friendly writes)
    k_hist<<<NCHUNK, 256, 0, stream>>>(ei, histT);
    k_bbase<<<1, 256, 0, stream>>>(histT, bbase, rowptr);
    k_bscan<<<NBKT, 256, 0, stream>>>(histT, bbase, offT);
    k_scatter<<<NCHUNK, 256, 0, stream>>>(ei, offT, rec);
    k_bfill<<<NBKT, 256, 0, stream>>>(rec, bbase, rowptr, dinv, colsrc);

    const int GB = (NNODES + 63) / 64;
    const int AB = (NNODES + 3) / 4;
    const int PB = (NNODES * 128 / 4) / 256;

    // Layer 1
    k_mfma_gemm<128><<<GB, 256, 0, stream>>>(Hb, Wp1, dinv, Bm, NNODES);
    k_agg128b<<<AB, 256, 0, stream>>>(Bm, dinv, rowptr, colsrc, b1, A);
    k_bn_stats<<<1024, 256, 0, stream>>>(A, sums1, sumsq1);
    k_bn_final<<<1, 128, 0, stream>>>(sums1, sumsq1, g1, be1, scale, shift);
    k_bn_apply_b<<<PB, 256, 0, stream>>>(A, scale, shift, Hb);

    // Layer 2
    k_mfma_gemm<128><<<GB, 256, 0, stream>>>(Hb, Wp2, dinv, Bm, NNODES);
    k_agg128b<<<AB, 256, 0, stream>>>(Bm, dinv, rowptr, colsrc, b2, A);
    k_bn_stats<<<1024, 256, 0, stream>>>(A, sums2, sumsq2);
    k_bn_final<<<1, 128, 0, stream>>>(sums2, sumsq2, g2, be2, scale, shift);
    k_bn_apply_fb<<<PB, 256, 0, stream>>>(A, scale, shift, out_h, Hb);

    // Layer 3
    k_mfma_gemm<64><<<GB, 256, 0, stream>>>(Hb, Wp3, dinv, Bm, NNODES);
    k_agg64b<<<AB, 256, 0, stream>>>(Bm, dinv, rowptr, colsrc, b3, out_o);
}

// Round 5
// 460.392 us; speedup vs baseline: 3.0042x; 1.2514x over previous
//
#include <hip/hip_runtime.h>
#include <hip/hip_bf16.h>

#define NNODES 100000
#define NEDGES 1600000
#define EPSBN 1e-5f

// CSR build via bucketed counting sort
#define BKT_SHIFT 9
#define NODES_PER_BKT 512
#define NBKT 196
#define NCHUNK 256
#define CHUNK 6250
#define SRC_MASK 0x1FFFF
#define NSLOT 64

typedef unsigned short u16;
typedef unsigned int u32;
typedef __bf16 bf16x8 __attribute__((ext_vector_type(8)));
typedef float floatx4 __attribute__((ext_vector_type(4)));

__device__ __forceinline__ u16 f2bf(float f) {
    unsigned int u = __float_as_uint(f);
    unsigned int r = (u + 0x7fffu + ((u >> 16) & 1u)) >> 16;
    return (u16)r;
}
__device__ __forceinline__ float bflo(unsigned int u) { return __uint_as_float(u << 16); }
__device__ __forceinline__ float bfhi(unsigned int u) { return __uint_as_float(u & 0xffff0000u); }

// ---------------- CSR build: bucketed counting sort ----------------

__global__ __launch_bounds__(256) void k_hist(const int* __restrict__ ei, int* __restrict__ histT) {
    __shared__ int h[NBKT];
    int tid = threadIdx.x;
    if (tid < NBKT) h[tid] = 0;
    __syncthreads();
    int base = blockIdx.x * CHUNK;
    for (int e = base + tid; e < base + CHUNK; e += 256) {
        int d = ei[NEDGES + e];
        atomicAdd(&h[d >> BKT_SHIFT], 1);
    }
    __syncthreads();
    if (tid < NBKT) histT[tid * NCHUNK + blockIdx.x] = h[tid];
}

__global__ __launch_bounds__(256) void k_bbase(const int* __restrict__ histT, int* __restrict__ bbase,
                                               int* __restrict__ rowptr) {
    __shared__ int sdata[256];
    int tid = threadIdx.x;
    int s = 0;
    if (tid < NBKT) {
        for (int g = 0; g < NCHUNK; ++g) s += histT[tid * NCHUNK + g];
    }
    int val = s;
    sdata[tid] = val;
    __syncthreads();
    for (int off = 1; off < 256; off <<= 1) {
        int add = (tid >= off) ? sdata[tid - off] : 0;
        __syncthreads();
        val += add;
        sdata[tid] = val;
        __syncthreads();
    }
    if (tid < NBKT) bbase[tid] = val - s;
    if (tid == 0) { bbase[NBKT] = NEDGES; rowptr[NNODES] = NEDGES; }
}

__global__ __launch_bounds__(256) void k_bscan(const int* __restrict__ histT, const int* __restrict__ bbase,
                                               int* __restrict__ offT) {
    __shared__ int sdata[256];
    int b = blockIdx.x;
    int g = threadIdx.x;
    int v = histT[b * NCHUNK + g];
    int val = v;
    sdata[g] = val;
    __syncthreads();
    for (int off = 1; off < 256; off <<= 1) {
        int add = (g >= off) ? sdata[g - off] : 0;
        __syncthreads();
        val += add;
        sdata[g] = val;
        __syncthreads();
    }
    offT[b * NCHUNK + g] = bbase[b] + (val - v);
}

__global__ __launch_bounds__(256) void k_scatter(const int* __restrict__ ei, const int* __restrict__ offT,
                                                 u32* __restrict__ rec) {
    __shared__ int cur[NBKT];
    int tid = threadIdx.x;
    if (tid < NBKT) cur[tid] = offT[tid * NCHUNK + blockIdx.x];
    __syncthreads();
    int base = blockIdx.x * CHUNK;
    for (int e = base + tid; e < base + CHUNK; e += 256) {
        int s = ei[e];
        int d = ei[NEDGES + e];
        int b = d >> BKT_SHIFT;
        int p = atomicAdd(&cur[b], 1);
        rec[p] = ((u32)(d & (NODES_PER_BKT - 1)) << 17) | (u32)s;
    }
}

__global__ __launch_bounds__(256) void k_bfill(const u32* __restrict__ rec, const int* __restrict__ bbase,
                                               int* __restrict__ rowptr, float* __restrict__ dinv,
                                               int* __restrict__ colsrc) {
    __shared__ int cnt[NODES_PER_BKT];
    __shared__ int sdata[256];
    int tid = threadIdx.x;
    int b = blockIdx.x;
    int n0 = b * NODES_PER_BKT;
    int r0 = bbase[b], r1 = bbase[b + 1];
    cnt[2 * tid] = 0;
    cnt[2 * tid + 1] = 0;
    __syncthreads();
    for (int r = r0 + tid; r < r1; r += 256) {
        atomicAdd(&cnt[rec[r] >> 17], 1);
    }
    __syncthreads();
    int c0 = cnt[2 * tid], c1 = cnt[2 * tid + 1];
    int ps = c0 + c1;
    int val = ps;
    sdata[tid] = val;
    __syncthreads();
    for (int off = 1; off < 256; off <<= 1) {
        int add = (tid >= off) ? sdata[tid - off] : 0;
        __syncthreads();
        val += add;
        sdata[tid] = val;
        __syncthreads();
    }
    int e0 = val - ps;
    int e1 = e0 + c0;
    int na = n0 + 2 * tid, nb2 = n0 + 2 * tid + 1;
    if (na < NNODES) {
        rowptr[na] = r0 + e0;
        dinv[na] = rsqrtf((float)(c0 + 1));
    }
    if (nb2 < NNODES) {
        rowptr[nb2] = r0 + e1;
        dinv[nb2] = rsqrtf((float)(c1 + 1));
    }
    cnt[2 * tid] = r0 + e0;
    cnt[2 * tid + 1] = r0 + e1;
    __syncthreads();
    for (int r = r0 + tid; r < r1; r += 256) {
        u32 u = rec[r];
        int p = atomicAdd(&cnt[u >> 17], 1);
        colsrc[p] = (int)(u & SRC_MASK);
    }
}

// ---------------- pack all W into B-fragment layout ----------------

template <int COUT>
__device__ __forceinline__ void packone(const float* __restrict__ W, u16* __restrict__ Wp, int f) {
    constexpr int CT = COUT / 16;
    if (f >= 4 * CT * 64) return;
    int ks = f / (CT * 64);
    int ct = (f / 64) % CT;
    int lane = f % 64;
    int quad = lane >> 4, mm = lane & 15;
#pragma unroll
    for (int j = 0; j < 8; ++j) {
        float v = W[(size_t)(ks * 32 + quad * 8 + j) * COUT + ct * 16 + mm];
        Wp[(size_t)f * 8 + j] = f2bf(v);
    }
}

__global__ __launch_bounds__(256) void k_packW_all(const float* __restrict__ W1, const float* __restrict__ W2,
                                                   const float* __restrict__ W3, u16* __restrict__ Wp1,
                                                   u16* __restrict__ Wp2, u16* __restrict__ Wp3) {
    int b = blockIdx.x;
    if (b < 8) packone<128>(W1, Wp1, b * 256 + threadIdx.x);
    else if (b < 16) packone<128>(W2, Wp2, (b - 8) * 256 + threadIdx.x);
    else packone<64>(W3, Wp3, (b - 16) * 256 + threadIdx.x);
}

// ---------------- MFMA GEMM (fp32 input, optional fused BN affine + ReLU + h-write) ----------------
// Bout[r][c] = bf16( dinv[r] * sum_k act(X[r][k])*W[k][c] ),  act = relu(scale*x+shift) if AFFINE

template <int COUT, bool AFFINE, bool WRITEH>
__global__ __launch_bounds__(256) void k_mfma_gemm(const float* __restrict__ Xf, const u16* __restrict__ Wp,
                                                   const float* __restrict__ dinv,
                                                   const float* __restrict__ scale, const float* __restrict__ shift,
                                                   u16* __restrict__ Bout, float* __restrict__ Hout) {
    constexpr int CT = COUT / 16;
    const int wave = threadIdx.x >> 6;
    const int lane = threadIdx.x & 63;
    const int quad = lane >> 4;
    const int m = lane & 15;
    const int rowbase = blockIdx.x * 64 + wave * 16;
    const int arow = rowbase + m;
    const bool rv = arow < NNODES;
    floatx4 acc[CT];
#pragma unroll
    for (int ct = 0; ct < CT; ++ct) acc[ct] = floatx4{0.f, 0.f, 0.f, 0.f};
#pragma unroll
    for (int ks = 0; ks < 4; ++ks) {
        const int k0 = ks * 32 + quad * 8;
        float4 xa = make_float4(0.f, 0.f, 0.f, 0.f), xb = xa;
        if (rv) {
            xa = *(const float4*)(Xf + (size_t)arow * 128 + k0);
            xb = *(const float4*)(Xf + (size_t)arow * 128 + k0 + 4);
        }
        if (AFFINE) {
            float4 sa = *(const float4*)(scale + k0), sb = *(const float4*)(scale + k0 + 4);
            float4 ha = *(const float4*)(shift + k0), hb = *(const float4*)(shift + k0 + 4);
            xa.x = fmaxf(fmaf(xa.x, sa.x, ha.x), 0.f);
            xa.y = fmaxf(fmaf(xa.y, sa.y, ha.y), 0.f);
            xa.z = fmaxf(fmaf(xa.z, sa.z, ha.z), 0.f);
            xa.w = fmaxf(fmaf(xa.w, sa.w, ha.w), 0.f);
            xb.x = fmaxf(fmaf(xb.x, sb.x, hb.x), 0.f);
            xb.y = fmaxf(fmaf(xb.y, sb.y, hb.y), 0.f);
            xb.z = fmaxf(fmaf(xb.z, sb.z, hb.z), 0.f);
            xb.w = fmaxf(fmaf(xb.w, sb.w, hb.w), 0.f);
        }
        if (WRITEH && rv) {
            *(float4*)(Hout + (size_t)arow * 128 + k0) = xa;
            *(float4*)(Hout + (size_t)arow * 128 + k0 + 4) = xb;
        }
        union { u16 h[8]; bf16x8 v; } ua;
        ua.h[0] = f2bf(xa.x); ua.h[1] = f2bf(xa.y); ua.h[2] = f2bf(xa.z); ua.h[3] = f2bf(xa.w);
        ua.h[4] = f2bf(xb.x); ua.h[5] = f2bf(xb.y); ua.h[6] = f2bf(xb.z); ua.h[7] = f2bf(xb.w);
#pragma unroll
        for (int ct = 0; ct < CT; ++ct) {
            uint4 bv = *(const uint4*)(Wp + ((size_t)(ks * CT + ct) * 64 + lane) * 8);
            bf16x8 b = *(const bf16x8*)&bv;
            acc[ct] = __builtin_amdgcn_mfma_f32_16x16x32_bf16(ua.v, b, acc[ct], 0, 0, 0);
        }
    }
    float dv[4];
#pragma unroll
    for (int reg = 0; reg < 4; ++reg) {
        int r = rowbase + quad * 4 + reg;
        dv[reg] = (r < NNODES) ? dinv[r] : 0.f;
    }
#pragma unroll
    for (int ct = 0; ct < CT; ++ct) {
#pragma unroll
        for (int reg = 0; reg < 4; ++reg) {
            int r = rowbase + quad * 4 + reg;
            if (r < NNODES) Bout[(size_t)r * COUT + ct * 16 + m] = f2bf(dv[reg] * acc[ct][reg]);
        }
    }
}

// ---------------- Aggregation: uint4 gathers, 4 edges per wave-instr, fused BN stats ----------------
// Out[d][c] = dinv[d]*(B[d][c] + sum_s B[s][c]) + bias[c]; logical index 0 = self-loop.

template <bool STATS>
__global__ __launch_bounds__(256) void k_agg128v(const u16* __restrict__ Bm, const float* __restrict__ dinv,
                                                 const int* __restrict__ rowptr, const int* __restrict__ colsrc,
                                                 const float* __restrict__ bias, float* __restrict__ Out,
                                                 float* __restrict__ slots) {
    __shared__ float sO[4][128];
    const int wave = threadIdx.x >> 6;
    const int node = blockIdx.x * 4 + wave;
    const int lane = threadIdx.x & 63;
    const int g = lane >> 4;     // edge slot within gather group
    const int c16 = lane & 15;   // channel block: channels c16*8 .. +7
    const uint4* Bq = (const uint4*)Bm;
    float a0[8], a1[8];
#pragma unroll
    for (int j = 0; j < 8; ++j) { a0[j] = 0.f; a1[j] = 0.f; }
    const int beg = rowptr[node];
    const int L = rowptr[node + 1] - beg + 1;  // edges + self
    for (int it = 0; it < L; it += 8) {
        int i0 = it + g, i1 = it + 4 + g;
        float w0 = (i0 < L) ? 1.f : 0.f;
        float w1 = (i1 < L) ? 1.f : 0.f;
        i0 = min(i0, L - 1);
        i1 = min(i1, L - 1);
        int s0 = colsrc[beg + max(i0, 1) - 1];
        int s1 = colsrc[beg + max(i1, 1) - 1];
        if (i0 == 0) s0 = node;  // self (only it==0, g==0)
        uint4 q0 = Bq[(size_t)s0 * 16 + c16];
        uint4 q1 = Bq[(size_t)s1 * 16 + c16];
        a0[0] += w0 * bflo(q0.x); a0[1] += w0 * bfhi(q0.x);
        a0[2] += w0 * bflo(q0.y); a0[3] += w0 * bfhi(q0.y);
        a0[4] += w0 * bflo(q0.z); a0[5] += w0 * bfhi(q0.z);
        a0[6] += w0 * bflo(q0.w); a0[7] += w0 * bfhi(q0.w);
        a1[0] += w1 * bflo(q1.x); a1[1] += w1 * bfhi(q1.x);
        a1[2] += w1 * bflo(q1.y); a1[3] += w1 * bfhi(q1.y);
        a1[4] += w1 * bflo(q1.z); a1[5] += w1 * bfhi(q1.z);
        a1[6] += w1 * bflo(q1.w); a1[7] += w1 * bfhi(q1.w);
    }
    const float dv = dinv[node];
    float o[8];
#pragma unroll
    for (int j = 0; j < 8; ++j) {
        float s = a0[j] + a1[j];
        s += __shfl_xor(s, 16);
        s += __shfl_xor(s, 32);
        o[j] = dv * s + bias[c16 * 8 + j];
    }
    if (g == 0) {
        float4 v0 = make_float4(o[0], o[1], o[2], o[3]);
        float4 v1 = make_float4(o[4], o[5], o[6], o[7]);
        *(float4*)(Out + (size_t)node * 128 + c16 * 8) = v0;
        *(float4*)(Out + (size_t)node * 128 + c16 * 8 + 4) = v1;
        if (STATS) {
#pragma unroll
            for (int j = 0; j < 8; ++j) sO[wave][c16 * 8 + j] = o[j];
        }
    }
    if (STATS) {
        __syncthreads();
        if (threadIdx.x < 128) {
            float s = 0.f, q = 0.f;
#pragma unroll
            for (int wv = 0; wv < 4; ++wv) {
                float v = sO[wv][threadIdx.x];
                s += v;
                q += v * v;
            }
            float* slot = slots + (size_t)(blockIdx.x & (NSLOT - 1)) * 256;
            atomicAdd(&slot[threadIdx.x], s);
            atomicAdd(&slot[128 + threadIdx.x], q);
        }
    }
}

__global__ __launch_bounds__(256) void k_agg64v(const u16* __restrict__ Bm, const float* __restrict__ dinv,
                                                const int* __restrict__ rowptr, const int* __restrict__ colsrc,
                                                const float* __restrict__ bias, float* __restrict__ Out) {
    const int node = blockIdx.x * 4 + (threadIdx.x >> 6);
    const int lane = threadIdx.x & 63;
    const int g = lane >> 3;    // 0..7 edge slots
    const int c8 = lane & 7;    // channels c8*8 .. +7
    const uint4* Bq = (const uint4*)Bm;
    float a0[8], a1[8];
#pragma unroll
    for (int j = 0; j < 8; ++j) { a0[j] = 0.f; a1[j] = 0.f; }
    const int beg = rowptr[node];
    const int L = rowptr[node + 1] - beg + 1;
    for (int it = 0; it < L; it += 16) {
        int i0 = it + g, i1 = it + 8 + g;
        float w0 = (i0 < L) ? 1.f : 0.f;
        float w1 = (i1 < L) ? 1.f : 0.f;
        i0 = min(i0, L - 1);
        i1 = min(i1, L - 1);
        int s0 = colsrc[beg + max(i0, 1) - 1];
        int s1 = colsrc[beg + max(i1, 1) - 1];
        if (i0 == 0) s0 = node;
        uint4 q0 = Bq[(size_t)s0 * 8 + c8];
        uint4 q1 = Bq[(size_t)s1 * 8 + c8];
        a0[0] += w0 * bflo(q0.x); a0[1] += w0 * bfhi(q0.x);
        a0[2] += w0 * bflo(q0.y); a0[3] += w0 * bfhi(q0.y);
        a0[4] += w0 * bflo(q0.z); a0[5] += w0 * bfhi(q0.z);
        a0[6] += w0 * bflo(q0.w); a0[7] += w0 * bfhi(q0.w);
        a1[0] += w1 * bflo(q1.x); a1[1] += w1 * bfhi(q1.x);
        a1[2] += w1 * bflo(q1.y); a1[3] += w1 * bfhi(q1.y);
        a1[4] += w1 * bflo(q1.z); a1[5] += w1 * bfhi(q1.z);
        a1[6] += w1 * bflo(q1.w); a1[7] += w1 * bfhi(q1.w);
    }
    const float dv = dinv[node];
    float o[8];
#pragma unroll
    for (int j = 0; j < 8; ++j) {
        float s = a0[j] + a1[j];
        s += __shfl_xor(s, 8);
        s += __shfl_xor(s, 16);
        s += __shfl_xor(s, 32);
        o[j] = dv * s + bias[c8 * 8 + j];
    }
    if (g == 0) {
        float4 v0 = make_float4(o[0], o[1], o[2], o[3]);
        float4 v1 = make_float4(o[4], o[5], o[6], o[7]);
        *(float4*)(Out + (size_t)node * 64 + c8 * 8) = v0;
        *(float4*)(Out + (size_t)node * 64 + c8 * 8 + 4) = v1;
    }
}

// ---------------- BN finalize: reduce slots -> scale/shift ----------------

__global__ void k_bn_final(const float* __restrict__ slots, const float* __restrict__ g,
                           const float* __restrict__ be, float* __restrict__ scale, float* __restrict__ shift) {
    int c = threadIdx.x;  // 128 threads
    float s = 0.f, q = 0.f;
    for (int k = 0; k < NSLOT; ++k) {
        s += slots[(size_t)k * 256 + c];
        q += slots[(size_t)k * 256 + 128 + c];
    }
    float mean = s * (1.0f / NNODES);
    float var = q * (1.0f / NNODES) - mean * mean;
    float istd = rsqrtf(var + EPSBN);
    float sc = g[c] * istd;
    scale[c] = sc;
    shift[c] = be[c] - sc * mean;
}

// ---------------- launch ----------------

extern "C" void kernel_launch(void* const* d_in, const int* in_sizes, int n_in,
                              void* d_out, int out_size, void* d_ws, size_t ws_size,
                              hipStream_t stream) {
    const float* x   = (const float*)d_in[0];
    const float* W1  = (const float*)d_in[1];
    const float* b1  = (const float*)d_in[2];
    const float* g1  = (const float*)d_in[3];
    const float* be1 = (const float*)d_in[4];
    const float* W2  = (const float*)d_in[5];
    const float* b2  = (const float*)d_in[6];
    const float* g2  = (const float*)d_in[7];
    const float* be2 = (const float*)d_in[8];
    const float* W3  = (const float*)d_in[9];
    const float* b3  = (const float*)d_in[10];
    const int* ei    = (const int*)d_in[11];

    float* out_h = (float*)d_out;                        // [N,128] h2
    float* out_o = (float*)d_out + (size_t)NNODES * 128; // [N,64]  conv3 out

    char* w = (char*)d_ws;
    float* A = (float*)w;      w += (size_t)NNODES * 128 * 4;   // fp32 post-agg
    u16* Bm = (u16*)w;         w += (size_t)NNODES * 128 * 2;   // bf16 messages
    float* dinv = (float*)w;   w += (size_t)NNODES * 4;
    int* rowptr = (int*)w;     w += (size_t)(NNODES + 32) * 4;
    int* colsrc = (int*)w;     w += (size_t)(NEDGES + 8) * 4;   // +pad for clamped tail reads
    int* bbase = (int*)w;      w += (NBKT + 4) * 4;
    float* slots1 = (float*)w; w += (size_t)NSLOT * 256 * 4;
    float* slots2 = (float*)w; w += (size_t)NSLOT * 256 * 4;
    float* scale = (float*)w;  w += 128 * 4;
    float* shift = (float*)w;  w += 128 * 4;
    u16* Wp1 = (u16*)w;        w += 128 * 128 * 2;
    u16* Wp2 = (u16*)w;        w += 128 * 128 * 2;
    u16* Wp3 = (u16*)w;        w += 128 * 64 * 2;

    // Build-phase scratch aliased onto buffers dead until layer 1:
    u32* rec  = (u32*)A;                        // [NEDGES]
    int* histT = (int*)Bm;                      // [NBKT*NCHUNK]
    int* offT  = (int*)Bm + NBKT * NCHUNK;      // [NBKT*NCHUNK]

    hipMemsetAsync(slots1, 0, (size_t)2 * NSLOT * 256 * 4, stream);

    k_packW_all<<<20, 256, 0, stream>>>(W1, W2, W3, Wp1, Wp2, Wp3);

    // CSR build
    k_hist<<<NCHUNK, 256, 0, stream>>>(ei, histT);
    k_bbase<<<1, 256, 0, stream>>>(histT, bbase, rowptr);
    k_bscan<<<NBKT, 256, 0, stream>>>(histT, bbase, offT);
    k_scatter<<<NCHUNK, 256, 0, stream>>>(ei, offT, rec);
    k_bfill<<<NBKT, 256, 0, stream>>>(rec, bbase, rowptr, dinv, colsrc);

    const int GB = (NNODES + 63) / 64;   // 1563
    const int AB = NNODES / 4;           // 25000

    // Layer 1: x (fp32) -> Bm -> A1 (+stats1)
    k_mfma_gemm<128, false, false><<<GB, 256, 0, stream>>>(x, Wp1, dinv, nullptr, nullptr, Bm, nullptr);
    k_agg128v<true><<<AB, 256, 0, stream>>>(Bm, dinv, rowptr, colsrc, b1, A, slots1);
    k_bn_final<<<1, 128, 0, stream>>>(slots1, g1, be1, scale, shift);

    // Layer 2: A1 (BN1+ReLU inline) -> Bm -> A2 (+stats2)
    k_mfma_gemm<128, true, false><<<GB, 256, 0, stream>>>(A, Wp2, dinv, scale, shift, Bm, nullptr);
    k_agg128v<true><<<AB, 256, 0, stream>>>(Bm, dinv, rowptr, colsrc, b2, A, slots2);
    k_bn_final<<<1, 128, 0, stream>>>(slots2, g2, be2, scale, shift);

    // Layer 3: A2 (BN2+ReLU inline, h2 written as byproduct) -> Bm64 -> out_o
    k_mfma_gemm<64, true, true><<<GB, 256, 0, stream>>>(A, Wp3, dinv, scale, shift, Bm, out_h);
    k_agg64v<<<AB, 256, 0, stream>>>(Bm, dinv, rowptr, colsrc, b3, out_o);
}